// Round 3
// baseline (17467.772 us; speedup 1.0000x reference)
//
#include <hip/hip_runtime.h>
#include <math.h>

#define SQHf 0.70710678118654752440f

__device__ __forceinline__ void d_t2ij(int t, int& i, int& j) {
    float f = sqrtf(8.0f * (float)t + 1.0f);
    int r = (int)((f - 1.0f) * 0.5f);
    while (((r + 1) * (r + 2)) / 2 <= t) ++r;
    while ((r * (r + 1)) / 2 > t) --r;
    i = r;
    j = t - (r * (r + 1)) / 2;
}

// ---------- build two smat matrices from svec vectors ----------
__global__ void k_smat2(const float* __restrict__ v1, float* __restrict__ M1,
                        const float* __restrict__ v2, float* __restrict__ M2) {
    int idx = blockIdx.x * 256 + threadIdx.x;
    if (idx >= 9800) return;
    int which = idx / 4900;
    int e = idx - which * 4900;
    const float* v = which ? v2 : v1;
    float* M = which ? M2 : M1;
    int i = e / 70, j = e % 70;
    int hi = i > j ? i : j, lo = i > j ? j : i;
    float val = v[(hi * (hi + 1)) / 2 + lo];
    M[e] = (i == j) ? val : val * SQHf;
}

// ---------- Cholesky of two 70x70 SPD matrices -> upper factors R (A = R^T R) ----------
__global__ __launch_bounds__(256) void k_chol2(const float* __restrict__ A0, float* __restrict__ R0,
                                               const float* __restrict__ A1, float* __restrict__ R1) {
    const float* A = blockIdx.x ? A1 : A0;
    float* R = blockIdx.x ? R1 : R0;
    __shared__ float S[70][71];
    for (int e = threadIdx.x; e < 4900; e += 256) S[e / 70][e % 70] = A[e];
    __syncthreads();
    for (int k = 0; k < 70; ++k) {
        if (threadIdx.x == 0) S[k][k] = sqrtf(S[k][k]);
        __syncthreads();
        float d = S[k][k];
        for (int i = k + 1 + threadIdx.x; i < 70; i += 256) S[i][k] /= d;
        __syncthreads();
        for (int e = threadIdx.x; e < 4900; e += 256) {
            int i = e / 70, j = e % 70;
            if (j > k && i >= j) S[i][j] -= S[i][k] * S[j][k];
        }
        __syncthreads();
    }
    // R = L^T (upper), zeros below
    for (int e = threadIdx.x; e < 4900; e += 256) {
        int i = e / 70, j = e % 70;
        R[e] = (i <= j) ? S[j][i] : 0.0f;
    }
}

// ---------- inverse of two upper-triangular 70x70 ----------
__global__ __launch_bounds__(256) void k_trinv2(const float* __restrict__ R0, float* __restrict__ O0,
                                                const float* __restrict__ R1, float* __restrict__ O1) {
    const float* R = blockIdx.x ? R1 : R0;
    float* O = blockIdx.x ? O1 : O0;
    __shared__ float S[70][71];
    __shared__ float V[70][71];
    for (int e = threadIdx.x; e < 4900; e += 256) S[e / 70][e % 70] = R[e];
    __syncthreads();
    int j = threadIdx.x;
    if (j < 70) {
        for (int i = j; i >= 0; --i) {
            float s = (i == j) ? 1.0f : 0.0f;
            for (int k = i + 1; k <= j; ++k) s -= S[i][k] * V[j][k];
            V[j][i] = s / S[i][i];
        }
    }
    __syncthreads();
    for (int e = threadIdx.x; e < 4900; e += 256) {
        int i = e / 70, jj = e % 70;
        O[e] = (i <= jj) ? V[jj][i] : 0.0f;
    }
}

// ---------- generic 70x70 matmul C = op(A)*op(B) ----------
__global__ __launch_bounds__(256) void k_mm70(const float* __restrict__ A, int tA,
                                              const float* __restrict__ B, int tB,
                                              float* __restrict__ C) {
    __shared__ float As[70][71], Bs[70][71];
    for (int e = threadIdx.x; e < 4900; e += 256) {
        int i = e / 70, j = e % 70;
        As[i][j] = tA ? A[j * 70 + i] : A[e];
        Bs[i][j] = tB ? B[j * 70 + i] : B[e];
    }
    __syncthreads();
    for (int e = threadIdx.x; e < 4900; e += 256) {
        int i = e / 70, j = e % 70;
        float s = 0.0f;
        for (int k = 0; k < 70; ++k) s += As[i][k] * Bs[k][j];
        C[e] = s;
    }
}

// ---------- GEMV with A row-major: out[row] = add +/- A.row dot v ----------
__global__ __launch_bounds__(256) void k_gemv_rowA(const float* __restrict__ A, long lda, int Kdim,
                                                   const float* __restrict__ v, const float* __restrict__ add,
                                                   float sgn, float* __restrict__ out) {
    int row = blockIdx.x;
    const float* Ar = A + (long)row * lda;
    float s = 0.0f;
    for (int k = threadIdx.x; k < Kdim; k += 256) s += Ar[k] * v[k];
    __shared__ float red[256];
    red[threadIdx.x] = s;
    __syncthreads();
    for (int o = 128; o; o >>= 1) {
        if (threadIdx.x < o) red[threadIdx.x] += red[threadIdx.x + o];
        __syncthreads();
    }
    if (threadIdx.x == 0) out[row] = (add ? add[row] : 0.0f) + sgn * red[0];
}

// ---------- out[j] = add1 - add2 + sgn * (A^T w)[j], coalesced over columns ----------
__global__ __launch_bounds__(256) void k_gemv_colAT(const float* __restrict__ A, long lda, int M, int Ncols,
                                                    const float* __restrict__ w,
                                                    const float* __restrict__ add1, const float* __restrict__ add2,
                                                    float sgn, float* __restrict__ out) {
    int j = blockIdx.x * 256 + threadIdx.x;
    if (j >= Ncols) return;
    float s = 0.0f;
    for (int i = 0; i < M; ++i) s += A[(long)i * lda + j] * w[i];
    float base = (add1 ? add1[j] : 0.0f) - (add2 ? add2[j] : 0.0f);
    out[j] = base + sgn * s;
}

// ---------- sc[1] = x.z ; sc[0] = mu ----------
__global__ __launch_bounds__(256) void k_dots_init(const float* __restrict__ x, const float* __restrict__ z,
                                                   float* __restrict__ sc) {
    __shared__ float red[256];
    float s = 0.0f;
    for (int i = threadIdx.x; i < 2485; i += 256) s += x[i] * z[i];
    red[threadIdx.x] = s;
    __syncthreads();
    for (int o = 128; o; o >>= 1) {
        if (threadIdx.x < o) red[threadIdx.x] += red[threadIdx.x + o];
        __syncthreads();
    }
    if (threadIdx.x == 0) { sc[1] = red[0]; sc[0] = red[0] / 70.0f; }
}

// ---------- sc[7] = (x+alpha dx).(z+beta dz) ----------
__global__ __launch_bounds__(256) void k_dot_new(const float* __restrict__ x, const float* __restrict__ dx,
                                                 const float* __restrict__ z, const float* __restrict__ dz,
                                                 float* __restrict__ sc) {
    __shared__ float red[256];
    float a = sc[2], b = sc[3];
    float s = 0.0f;
    for (int i = threadIdx.x; i < 2485; i += 256)
        s += (x[i] + a * dx[i]) * (z[i] + b * dz[i]);
    red[threadIdx.x] = s;
    __syncthreads();
    for (int o = 128; o; o >>= 1) {
        if (threadIdx.x < o) red[threadIdx.x] += red[threadIdx.x + o];
        __syncthreads();
    }
    if (threadIdx.x == 0) sc[7] = red[0];
}

// ---------- Rc = -svec(sym(W)) ----------
__global__ void k_svec_rc(const float* __restrict__ W, float* __restrict__ out) {
    int t = blockIdx.x * 256 + threadIdx.x;
    if (t >= 2485) return;
    int i, j;
    d_t2ij(t, i, j);
    float v = (i == j) ? W[i * 70 + i] : (W[i * 70 + j] + W[j * 70 + i]) * SQHf;
    out[t] = -v;
}

// ---------- Rc2 = svec(sigmu*I - sym(W1) - sym(W2)) ----------
__global__ void k_svec_rc2(const float* __restrict__ W1, const float* __restrict__ W2,
                           const float* __restrict__ sc, float* __restrict__ out) {
    int t = blockIdx.x * 256 + threadIdx.x;
    if (t >= 2485) return;
    int i, j;
    d_t2ij(t, i, j);
    float sm = sc[13];
    if (i == j)
        out[t] = sm - W1[i * 70 + i] - W2[i * 70 + i];
    else
        out[t] = -(W1[i * 70 + j] + W1[j * 70 + i] + W2[i * 70 + j] + W2[j * 70 + i]) * SQHf;
}

// ---------- skmult: block l -> out row l = 0.5*svec(K*smat(a_l)*G^T + transpose) ----------
__global__ __launch_bounds__(256) void k_skmult(const float* __restrict__ K, const float* __restrict__ G,
                                                const float* __restrict__ Arows, long ldA,
                                                float* __restrict__ outT, long ldOut) {
    int l = blockIdx.x;
    const float* a = Arows + (long)l * ldA;
    float* out = outT + (long)l * ldOut;
    __shared__ float S[70][71];
    __shared__ float T1[70][71];
    for (int e = threadIdx.x; e < 4900; e += 256) {
        int i = e / 70, j = e % 70;
        int hi = i > j ? i : j, lo = i > j ? j : i;
        float v = a[(hi * (hi + 1)) / 2 + lo];
        S[i][j] = (i == j) ? v : v * SQHf;
    }
    __syncthreads();
    // T1 = S * G^T
    for (int e = threadIdx.x; e < 4900; e += 256) {
        int i = e / 70, j = e % 70;
        const float* Gr = G + j * 70;
        float s = 0.0f;
        for (int k = 0; k < 70; ++k) s += S[i][k] * Gr[k];
        T1[i][j] = s;
    }
    __syncthreads();
    // W = K*T1 ; out[t] = svec_sym(W)
    for (int t = threadIdx.x; t < 2485; t += 256) {
        int i, j;
        d_t2ij(t, i, j);
        const float* Ki = K + i * 70;
        const float* Kj = K + j * 70;
        float wij = 0.0f, wji = 0.0f;
        for (int k = 0; k < 70; ++k) {
            wij += Ki[k] * T1[k][j];
            wji += Kj[k] * T1[k][i];
        }
        out[t] = (i == j) ? wij : (wij + wji) * SQHf;
    }
}

// ---------- tiled fp32 GEMM: C = beta*C + alpha * A * B^T (both row-major, NT) ----------
#define GBM 64
#define GBK 32
__global__ __launch_bounds__(256) void k_gemm_nt(const float* __restrict__ A, long lda,
                                                 const float* __restrict__ B, long ldb,
                                                 float* __restrict__ C, long ldc,
                                                 int M, int N, int Kd,
                                                 float alpha, float beta, int lower_only) {
    int bx = blockIdx.x, by = blockIdx.y;
    int row0 = by * GBM, col0 = bx * GBM;
    if (lower_only && col0 > row0 + GBM - 1) return;
    __shared__ float As[GBM][GBK + 1], Bs[GBM][GBK + 1];
    int tid = threadIdx.x;
    int tx = tid % 16, ty = tid / 16;
    float acc[4][4] = {{0.f}};
    for (int k0 = 0; k0 < Kd; k0 += GBK) {
        for (int e = tid; e < GBM * GBK; e += 256) {
            int r = e / GBK, cc = e % GBK;
            int gr = row0 + r, gc = k0 + cc;
            As[r][cc] = (gr < M && gc < Kd) ? A[(long)gr * lda + gc] : 0.0f;
        }
        for (int e = tid; e < GBM * GBK; e += 256) {
            int r = e / GBK, cc = e % GBK;
            int gr = col0 + r, gc = k0 + cc;
            Bs[r][cc] = (gr < N && gc < Kd) ? B[(long)gr * ldb + gc] : 0.0f;
        }
        __syncthreads();
        for (int kk = 0; kk < GBK; ++kk) {
            float av[4], bv[4];
#pragma unroll
            for (int m = 0; m < 4; ++m) av[m] = As[ty * 4 + m][kk];
#pragma unroll
            for (int n = 0; n < 4; ++n) bv[n] = Bs[tx * 4 + n][kk];
#pragma unroll
            for (int m = 0; m < 4; ++m)
#pragma unroll
                for (int n = 0; n < 4; ++n) acc[m][n] += av[m] * bv[n];
        }
        __syncthreads();
    }
#pragma unroll
    for (int m = 0; m < 4; ++m)
#pragma unroll
        for (int n = 0; n < 4; ++n) {
            int gr = row0 + ty * 4 + m, gc = col0 + tx * 4 + n;
            if (gr < M && gc < N) {
                float* cp = &C[(long)gr * ldc + gc];
                if (beta != 0.0f) *cp = beta * (*cp) + alpha * acc[m][n];
                else *cp = alpha * acc[m][n];
            }
        }
}

// ---------- blocked Cholesky: diagonal block factor ----------
__global__ __launch_bounds__(256) void k_chol_diag(float* __restrict__ Mp, long ld, int jb, int nb) {
    __shared__ float S[64][65];
    for (int e = threadIdx.x; e < nb * nb; e += 256) {
        int i = e / nb, j = e % nb;
        S[i][j] = Mp[(long)(jb + i) * ld + jb + j];
    }
    __syncthreads();
    for (int k = 0; k < nb; ++k) {
        if (threadIdx.x == 0) S[k][k] = sqrtf(S[k][k]);
        __syncthreads();
        float d = S[k][k];
        for (int i = k + 1 + threadIdx.x; i < nb; i += 256) S[i][k] /= d;
        __syncthreads();
        for (int e = threadIdx.x; e < nb * nb; e += 256) {
            int i = e / nb, j = e % nb;
            if (j > k && i >= j) S[i][j] -= S[i][k] * S[j][k];
        }
        __syncthreads();
    }
    for (int e = threadIdx.x; e < nb * nb; e += 256) {
        int i = e / nb, j = e % nb;
        if (i >= j) Mp[(long)(jb + i) * ld + jb + j] = S[i][j];
    }
}

// ---------- blocked Cholesky: panel triangular solve (rows below diag block) ----------
__global__ __launch_bounds__(256) void k_chol_panel(float* __restrict__ Mp, long ld, int jb, int nb, int n) {
    __shared__ float L11[64][65];
    __shared__ float Pn[128][65];
    int r0 = jb + nb + blockIdx.x * 128;
    int nrows = n - r0;
    if (nrows > 128) nrows = 128;
    if (nrows <= 0) return;
    for (int e = threadIdx.x; e < nb * nb; e += 256) {
        int i = e / nb, j = e % nb;
        L11[i][j] = Mp[(long)(jb + i) * ld + jb + j];
    }
    for (int e = threadIdx.x; e < nrows * nb; e += 256) {
        int i = e / nb, j = e % nb;
        Pn[i][j] = Mp[(long)(r0 + i) * ld + jb + j];
    }
    __syncthreads();
    for (int k = 0; k < nb; ++k) {
        float dk = L11[k][k];
        for (int i = threadIdx.x; i < nrows; i += 256) {
            float v = Pn[i][k];
            for (int m = 0; m < k; ++m) v -= Pn[i][m] * L11[k][m];
            Pn[i][k] = v / dk;
        }
        __syncthreads();
    }
    for (int e = threadIdx.x; e < nrows * nb; e += 256) {
        int i = e / nb, j = e % nb;
        Mp[(long)(r0 + i) * ld + jb + j] = Pn[i][j];
    }
}

// ---------- SPD solve: L L^T x = b (single block, blocked fwd + bwd) ----------
__global__ __launch_bounds__(1024) void k_spdsolve(const float* __restrict__ L, long ld, int n,
                                                   const float* __restrict__ bin, float* __restrict__ xout) {
    __shared__ float bv[2048];
    __shared__ float Dg[64][65];
    int tid = threadIdx.x;
    for (int i = tid; i < n; i += 1024) bv[i] = bin[i];
    __syncthreads();
    // forward: L y = b
    for (int jb = 0; jb < n; jb += 64) {
        int nb = n - jb < 64 ? n - jb : 64;
        for (int e = tid; e < nb * nb; e += 1024) {
            int i = e / nb, j = e % nb;
            Dg[i][j] = L[(long)(jb + i) * ld + jb + j];
        }
        __syncthreads();
        for (int k = 0; k < nb; ++k) {
            float part = 0.0f;
            if (tid < 64) {
                if (tid < k) part = Dg[k][tid] * bv[jb + tid];
                for (int o = 32; o; o >>= 1) part += __shfl_down(part, o);
                if (tid == 0) bv[jb + k] = (bv[jb + k] - part) / Dg[k][k];
            }
            __syncthreads();
        }
        for (int i = jb + nb + tid; i < n; i += 1024) {
            const float4* Lr4 = (const float4*)(L + (long)i * ld + jb);
            float acc = 0.0f;
            for (int m = 0; m < nb / 4; ++m) {
                float4 q = Lr4[m];
                acc += q.x * bv[jb + 4 * m] + q.y * bv[jb + 4 * m + 1] + q.z * bv[jb + 4 * m + 2] + q.w * bv[jb + 4 * m + 3];
            }
            bv[i] -= acc;
        }
        __syncthreads();
    }
    // backward: L^T x = y
    for (int jb = ((n - 1) / 64) * 64; jb >= 0; jb -= 64) {
        int nb = n - jb < 64 ? n - jb : 64;
        for (int e = tid; e < nb * nb; e += 1024) {
            int i = e / nb, j = e % nb;
            Dg[i][j] = L[(long)(jb + i) * ld + jb + j];
        }
        __syncthreads();
        for (int k = nb - 1; k >= 0; --k) {
            float part = 0.0f;
            if (tid < 64) {
                if (tid > k && tid < nb) part = Dg[tid][k] * bv[jb + tid];
                for (int o = 32; o; o >>= 1) part += __shfl_down(part, o);
                if (tid == 0) bv[jb + k] = (bv[jb + k] - part) / Dg[k][k];
            }
            __syncthreads();
        }
        for (int i = tid; i < jb; i += 1024) {
            float acc = 0.0f;
            for (int m = 0; m < nb; ++m) acc += L[(long)(jb + m) * ld + i] * bv[jb + m];
            bv[i] -= acc;
        }
        __syncthreads();
    }
    for (int i = tid; i < n; i += 1024) xout[i] = bv[i];
}

// ---------- parallel cyclic Jacobi (tournament), smallest eigenvalue of two 70x70 ----------
__device__ __forceinline__ int jac_f(int i, int r) {
    return (i == 0) ? 0 : 1 + ((i - 1 + r) % 69);
}
__global__ __launch_bounds__(256) void k_jacobi2(const float* __restrict__ E0, const float* __restrict__ E1f,
                                                 float* __restrict__ sc, int o0, int o1) {
    const float* E = blockIdx.x ? E1f : E0;
    int outi = blockIdx.x ? o1 : o0;
    __shared__ float Am[70][71];
    __shared__ float cs[35], sn[35];
    for (int e = threadIdx.x; e < 4900; e += 256) Am[e / 70][e % 70] = E[e];
    __syncthreads();
    for (int sw = 0; sw < 8; ++sw) {
        for (int r = 0; r < 69; ++r) {
            if (threadIdx.x < 35) {
                int p = jac_f(threadIdx.x, r), q = jac_f(69 - threadIdx.x, r);
                float app = Am[p][p], aqq = Am[q][q], apq = Am[p][q];
                float cc = 1.0f, ss = 0.0f;
                float denom = fabsf(app) + fabsf(aqq);
                if (fabsf(apq) > 1e-12f * denom + 1e-30f) {
                    float tau = (aqq - app) / (2.0f * apq);
                    float t = ((tau >= 0.0f) ? 1.0f : -1.0f) / (fabsf(tau) + sqrtf(1.0f + tau * tau));
                    cc = 1.0f / sqrtf(1.0f + t * t);
                    ss = t * cc;
                }
                cs[threadIdx.x] = cc;
                sn[threadIdx.x] = ss;
            }
            __syncthreads();
            for (int e = threadIdx.x; e < 2450; e += 256) {
                int pr = e / 70, col = e % 70;
                int p = jac_f(pr, r), q = jac_f(69 - pr, r);
                float cc = cs[pr], ss = sn[pr];
                float ap = Am[p][col], aq = Am[q][col];
                Am[p][col] = cc * ap - ss * aq;
                Am[q][col] = ss * ap + cc * aq;
            }
            __syncthreads();
            for (int e = threadIdx.x; e < 2450; e += 256) {
                int pr = e / 70, row = e % 70;
                int p = jac_f(pr, r), q = jac_f(69 - pr, r);
                float cc = cs[pr], ss = sn[pr];
                float ap = Am[row][p], aq = Am[row][q];
                Am[row][p] = cc * ap - ss * aq;
                Am[row][q] = ss * ap + cc * aq;
            }
            __syncthreads();
        }
    }
    __shared__ float red[256];
    float mn = 1e30f;
    for (int i = threadIdx.x; i < 70; i += 256) mn = fminf(mn, Am[i][i]);
    red[threadIdx.x] = mn;
    __syncthreads();
    for (int o = 128; o; o >>= 1) {
        if (threadIdx.x < o) red[threadIdx.x] = fminf(red[threadIdx.x], red[threadIdx.x + o]);
        __syncthreads();
    }
    if (threadIdx.x == 0) sc[outi] = red[0];
}

// ---------- scalar kernels ----------
__global__ void k_pred_scalars(float* sc) {
    float l0a = sc[11], l0b = sc[12];
    float sa = (l0a < 0.0f) ? -1.0f / l0a : 20.0f;
    float sb = (l0b < 0.0f) ? -1.0f / l0b : 20.0f;
    float alpha = fminf(0.5f, 0.9f * sa);
    float beta = fminf(0.5f, 0.9f * sb);
    float minab = fminf(alpha, beta);
    sc[2] = alpha;
    sc[3] = beta;
    sc[4] = minab;
    float mu = sc[0];
    sc[5] = (mu > 1e-6f && minab >= 0.57735026918962576f) ? fmaxf(1.0f, 3.0f * minab * minab) : 1.0f;
}
__global__ void k_sigma(float* sc) {
    float dn = sc[7], xz = sc[1], e = sc[5];
    float frac = dn / xz;
    float fs = (dn < 0.0f) ? 1.0f : frac;
    float sig = (dn < 0.0f) ? 0.8f : fminf(1.0f, powf(fs, e));
    sc[6] = sig;
    sc[13] = sig * sc[0];
    sc[8] = 0.9f + 0.09f * sc[4];
}
__global__ void k_corr_scalars(float* sc) {
    float g2 = sc[8];
    float l0a = sc[14], l0b = sc[15];
    float sa = (l0a < 0.0f) ? -1.0f / l0a : 20.0f;
    float sb = (l0b < 0.0f) ? -1.0f / l0b : 20.0f;
    sc[9] = fminf(0.5f, g2 * sa);
    sc[10] = fminf(0.5f, g2 * sb);
}

// ---------- out = a*u + b*v ----------
__global__ void k_axpby(const float* __restrict__ u, const float* __restrict__ v,
                        float a, float b, float* __restrict__ out, int n) {
    int i = blockIdx.x * 256 + threadIdx.x;
    if (i < n) out[i] = a * u[i] + b * v[i];
}

// ---------- final outputs ----------
__global__ void k_final(const float* __restrict__ x, const float* __restrict__ y, const float* __restrict__ z,
                        const float* __restrict__ dx2, const float* __restrict__ dy2, const float* __restrict__ dz2,
                        const float* __restrict__ normc, const float* __restrict__ sc, float* __restrict__ out) {
    int i = blockIdx.x * 256 + threadIdx.x;
    float a2 = sc[9], b2 = sc[10];
    if (i < 2485) out[i] = x[i] + a2 * dx2[i];
    else if (i < 4485) { int j = i - 2485; out[i] = y[j] + b2 * dy2[j]; }
    else if (i < 6970) { int j = i - 4485; out[i] = z[j] + b2 * dz2[j]; }
    else if (i < 8970) { int j = i - 6970; out[i] = (y[j] + b2 * dy2[j]) * normc[0]; }
}

extern "C" void kernel_launch(void* const* d_in, const int* in_sizes, int n_in,
                              void* d_out, int out_size, void* d_ws, size_t ws_size,
                              hipStream_t stream) {
    const float* x = (const float*)d_in[0];
    const float* y = (const float*)d_in[1];
    const float* z = (const float*)d_in[2];
    const float* A = (const float*)d_in[3];
    const float* b = (const float*)d_in[4];
    const float* c = (const float*)d_in[5];
    const float* normc = (const float*)d_in[6];
    float* out = (float*)d_out;
    float* ws = (float*)d_ws;

    float* SKT = ws;                       // 2000 x 2485
    float* Mm = ws + 4970000;              // 2000 x 2000
    float* S0 = ws + 8970000;
    float* X = S0;
    float* Z = S0 + 4900;
    float* Qu = S0 + 9800;
    float* Pu = S0 + 14700;
    float* Qi = S0 + 19600;
    float* Pi = S0 + 24500;
    float* Zi = S0 + 29400;
    float* U = S0 + 34300;
    float* T1 = S0 + 39200;
    float* W1 = S0 + 44100;
    float* U2 = S0 + 49000;
    float* T2 = S0 + 53900;
    float* W2 = S0 + 58800;
    float* D1 = S0 + 63700;
    float* D2 = S0 + 68600;
    float* E1 = S0 + 73500;
    float* E2 = S0 + 78400;
    float* rp = S0 + 83300;
    float* h = S0 + 85300;
    float* dy = S0 + 87300;
    float* dy2 = S0 + 89300;
    float* h2 = S0 + 91300;
    float* Rd = S0 + 93300;
    float* Rc = S0 + 95785;
    float* k1 = S0 + 98270;
    float* k2 = S0 + 100755;
    float* dz = S0 + 103240;
    float* dx = S0 + 105725;
    float* Rc2 = S0 + 108210;
    float* k2b = S0 + 110695;
    float* dz2 = S0 + 113180;
    float* dx2 = S0 + 115665;
    float* tmpv = S0 + 118150;
    float* sc = S0 + 120635;

    // ---- setup: X, Z, factors, inverses ----
    k_smat2<<<39, 256, 0, stream>>>(x, X, z, Z);
    k_chol2<<<2, 256, 0, stream>>>(X, Qu, Z, Pu);
    k_trinv2<<<2, 256, 0, stream>>>(Qu, Qi, Pu, Pi);
    k_mm70<<<1, 256, 0, stream>>>(Pi, 0, Pi, 1, Zi);   // Zinv = Pinv * Pinv^T

    // ---- residuals & mu ----
    k_gemv_rowA<<<2000, 256, 0, stream>>>(A, 2485L, 2485, x, b, -1.0f, rp);           // rp = b - A x
    k_gemv_colAT<<<10, 256, 0, stream>>>(A, 2485L, 2000, 2485, y, c, z, -1.0f, Rd);   // Rd = c - z - A^T y
    k_dots_init<<<1, 256, 0, stream>>>(x, z, sc);

    // ---- Rc = -svec(sym(P (XZ) Pinv)) ----
    k_mm70<<<1, 256, 0, stream>>>(X, 0, Z, 0, U);
    k_mm70<<<1, 256, 0, stream>>>(Pu, 0, U, 0, T1);
    k_mm70<<<1, 256, 0, stream>>>(T1, 0, Pi, 0, W1);
    k_svec_rc<<<10, 256, 0, stream>>>(W1, Rc);

    // ---- SKT = skmult(X, Zinv, A^T)^T ; Mmat = A * SKT^T (lower) ----
    k_skmult<<<2000, 256, 0, stream>>>(X, Zi, A, 2485L, SKT, 2485L);
    k_gemm_nt<<<dim3(32, 32), 256, 0, stream>>>(A, 2485L, SKT, 2485L, Mm, 2000L,
                                                2000, 2000, 2485, 1.0f, 0.0f, 1);

    // ---- Cholesky of Mmat (blocked, in-place lower) ----
    for (int jb = 0; jb < 2000; jb += 64) {
        int nb = (2000 - jb) < 64 ? (2000 - jb) : 64;
        k_chol_diag<<<1, 256, 0, stream>>>(Mm, 2000L, jb, nb);
        int rows = 2000 - jb - nb;
        if (rows > 0) {
            int pb = (rows + 127) / 128;
            k_chol_panel<<<pb, 256, 0, stream>>>(Mm, 2000L, jb, nb, 2000);
            int gb = (rows + 63) / 64;
            const float* pan = Mm + (size_t)(jb + nb) * 2000 + jb;
            float* csub = Mm + (size_t)(jb + nb) * 2000 + (jb + nb);
            k_gemm_nt<<<dim3(gb, gb), 256, 0, stream>>>(pan, 2000L, pan, 2000L, csub, 2000L,
                                                        rows, rows, nb, -1.0f, 1.0f, 1);
        }
    }

    // ---- predictor ----
    k_skmult<<<1, 256, 0, stream>>>(X, Zi, Rd, 0L, k1, 0L);
    k_skmult<<<1, 256, 0, stream>>>(Pi, Pi, Rc, 0L, k2, 0L);
    k_axpby<<<10, 256, 0, stream>>>(k1, k2, 1.0f, -1.0f, tmpv, 2485);
    k_gemv_rowA<<<2000, 256, 0, stream>>>(A, 2485L, 2485, tmpv, rp, 1.0f, h);
    k_spdsolve<<<1, 1024, 0, stream>>>(Mm, 2000L, 2000, h, dy);
    k_gemv_colAT<<<10, 256, 0, stream>>>(A, 2485L, 2000, 2485, dy, Rd, (const float*)0, -1.0f, dz);
    k_skmult<<<1, 256, 0, stream>>>(X, Zi, dz, 0L, tmpv, 0L);
    k_axpby<<<10, 256, 0, stream>>>(x, tmpv, -1.0f, -1.0f, dx, 2485);

    // ---- predictor step lengths ----
    k_smat2<<<39, 256, 0, stream>>>(dx, D1, dz, D2);
    k_mm70<<<1, 256, 0, stream>>>(Qi, 1, D1, 0, T2);
    k_mm70<<<1, 256, 0, stream>>>(T2, 0, Qi, 0, E1);
    k_mm70<<<1, 256, 0, stream>>>(Pi, 1, D2, 0, T2);
    k_mm70<<<1, 256, 0, stream>>>(T2, 0, Pi, 0, E2);
    k_jacobi2<<<2, 256, 0, stream>>>(E1, E2, sc, 11, 12);
    k_pred_scalars<<<1, 1, 0, stream>>>(sc);
    k_dot_new<<<1, 256, 0, stream>>>(x, dx, z, dz, sc);
    k_sigma<<<1, 1, 0, stream>>>(sc);

    // ---- corrector RHS ----
    k_mm70<<<1, 256, 0, stream>>>(D1, 0, D2, 0, U2);
    k_mm70<<<1, 256, 0, stream>>>(Pu, 0, U2, 0, T2);
    k_mm70<<<1, 256, 0, stream>>>(T2, 0, Pi, 0, W2);
    k_svec_rc2<<<10, 256, 0, stream>>>(W1, W2, sc, Rc2);
    k_skmult<<<1, 256, 0, stream>>>(Pi, Pi, Rc2, 0L, k2b, 0L);
    k_axpby<<<10, 256, 0, stream>>>(k1, k2b, 1.0f, -1.0f, tmpv, 2485);
    k_gemv_rowA<<<2000, 256, 0, stream>>>(A, 2485L, 2485, tmpv, rp, 1.0f, h2);
    k_spdsolve<<<1, 1024, 0, stream>>>(Mm, 2000L, 2000, h2, dy2);
    k_gemv_colAT<<<10, 256, 0, stream>>>(A, 2485L, 2000, 2485, dy2, Rd, (const float*)0, -1.0f, dz2);
    k_skmult<<<1, 256, 0, stream>>>(X, Zi, dz2, 0L, tmpv, 0L);
    k_axpby<<<10, 256, 0, stream>>>(k2b, tmpv, 1.0f, -1.0f, dx2, 2485);

    // ---- corrector step lengths ----
    k_smat2<<<39, 256, 0, stream>>>(dx2, D1, dz2, D2);
    k_mm70<<<1, 256, 0, stream>>>(Qi, 1, D1, 0, T2);
    k_mm70<<<1, 256, 0, stream>>>(T2, 0, Qi, 0, E1);
    k_mm70<<<1, 256, 0, stream>>>(Pi, 1, D2, 0, T2);
    k_mm70<<<1, 256, 0, stream>>>(T2, 0, Pi, 0, E2);
    k_jacobi2<<<2, 256, 0, stream>>>(E1, E2, sc, 14, 15);
    k_corr_scalars<<<1, 1, 0, stream>>>(sc);

    // ---- outputs ----
    k_final<<<36, 256, 0, stream>>>(x, y, z, dx2, dy2, dz2, normc, sc, out);
}

// Round 4
// 12677.991 us; speedup vs baseline: 1.3778x; 1.3778x over previous
//
#include <hip/hip_runtime.h>
#include <math.h>

#define SQHf 0.70710678118654752440f

__device__ __forceinline__ void d_t2ij(int t, int& i, int& j) {
    float f = sqrtf(8.0f * (float)t + 1.0f);
    int r = (int)((f - 1.0f) * 0.5f);
    while (((r + 1) * (r + 2)) / 2 <= t) ++r;
    while ((r * (r + 1)) / 2 > t) --r;
    i = r;
    j = t - (r * (r + 1)) / 2;
}

// ---------- build two smat matrices from svec vectors ----------
__global__ void k_smat2(const float* __restrict__ v1, float* __restrict__ M1,
                        const float* __restrict__ v2, float* __restrict__ M2) {
    int idx = blockIdx.x * 256 + threadIdx.x;
    if (idx >= 9800) return;
    int which = idx / 4900;
    int e = idx - which * 4900;
    const float* v = which ? v2 : v1;
    float* M = which ? M2 : M1;
    int i = e / 70, j = e % 70;
    int hi = i > j ? i : j, lo = i > j ? j : i;
    float val = v[(hi * (hi + 1)) / 2 + lo];
    M[e] = (i == j) ? val : val * SQHf;
}

// ---------- Cholesky of two 70x70 SPD matrices -> upper factors R (A = R^T R) ----------
__global__ __launch_bounds__(256) void k_chol2(const float* __restrict__ A0, float* __restrict__ R0,
                                               const float* __restrict__ A1, float* __restrict__ R1) {
    const float* A = blockIdx.x ? A1 : A0;
    float* R = blockIdx.x ? R1 : R0;
    __shared__ float S[70][71];
    for (int e = threadIdx.x; e < 4900; e += 256) S[e / 70][e % 70] = A[e];
    __syncthreads();
    for (int k = 0; k < 70; ++k) {
        if (threadIdx.x == 0) S[k][k] = sqrtf(S[k][k]);
        __syncthreads();
        float d = S[k][k];
        for (int i = k + 1 + threadIdx.x; i < 70; i += 256) S[i][k] /= d;
        __syncthreads();
        for (int e = threadIdx.x; e < 4900; e += 256) {
            int i = e / 70, j = e % 70;
            if (j > k && i >= j) S[i][j] -= S[i][k] * S[j][k];
        }
        __syncthreads();
    }
    for (int e = threadIdx.x; e < 4900; e += 256) {
        int i = e / 70, j = e % 70;
        R[e] = (i <= j) ? S[j][i] : 0.0f;
    }
}

// ---------- inverse of two upper-triangular 70x70 ----------
__global__ __launch_bounds__(256) void k_trinv2(const float* __restrict__ R0, float* __restrict__ O0,
                                                const float* __restrict__ R1, float* __restrict__ O1) {
    const float* R = blockIdx.x ? R1 : R0;
    float* O = blockIdx.x ? O1 : O0;
    __shared__ float S[70][71];
    __shared__ float V[70][71];
    for (int e = threadIdx.x; e < 4900; e += 256) S[e / 70][e % 70] = R[e];
    __syncthreads();
    int j = threadIdx.x;
    if (j < 70) {
        for (int i = j; i >= 0; --i) {
            float s = (i == j) ? 1.0f : 0.0f;
            for (int k = i + 1; k <= j; ++k) s -= S[i][k] * V[j][k];
            V[j][i] = s / S[i][i];
        }
    }
    __syncthreads();
    for (int e = threadIdx.x; e < 4900; e += 256) {
        int i = e / 70, jj = e % 70;
        O[e] = (i <= jj) ? V[jj][i] : 0.0f;
    }
}

// ---------- generic 70x70 matmul C = op(A)*op(B) ----------
__global__ __launch_bounds__(256) void k_mm70(const float* __restrict__ A, int tA,
                                              const float* __restrict__ B, int tB,
                                              float* __restrict__ C) {
    __shared__ float As[70][71], Bs[70][71];
    for (int e = threadIdx.x; e < 4900; e += 256) {
        int i = e / 70, j = e % 70;
        As[i][j] = tA ? A[j * 70 + i] : A[e];
        Bs[i][j] = tB ? B[j * 70 + i] : B[e];
    }
    __syncthreads();
    for (int e = threadIdx.x; e < 4900; e += 256) {
        int i = e / 70, j = e % 70;
        float s = 0.0f;
        for (int k = 0; k < 70; ++k) s += As[i][k] * Bs[k][j];
        C[e] = s;
    }
}

// ---------- GEMV with A row-major: out[row] = add +/- A.row dot v ----------
__global__ __launch_bounds__(256) void k_gemv_rowA(const float* __restrict__ A, long lda, int Kdim,
                                                   const float* __restrict__ v, const float* __restrict__ add,
                                                   float sgn, float* __restrict__ out) {
    int row = blockIdx.x;
    const float* Ar = A + (long)row * lda;
    float s = 0.0f;
    for (int k = threadIdx.x; k < Kdim; k += 256) s += Ar[k] * v[k];
    __shared__ float red[256];
    red[threadIdx.x] = s;
    __syncthreads();
    for (int o = 128; o; o >>= 1) {
        if (threadIdx.x < o) red[threadIdx.x] += red[threadIdx.x + o];
        __syncthreads();
    }
    if (threadIdx.x == 0) out[row] = (add ? add[row] : 0.0f) + sgn * red[0];
}

// ---------- out[j] = add1 - add2 + sgn * (A^T w)[j] ----------
__global__ __launch_bounds__(256) void k_gemv_colAT(const float* __restrict__ A, long lda, int M, int Ncols,
                                                    const float* __restrict__ w,
                                                    const float* __restrict__ add1, const float* __restrict__ add2,
                                                    float sgn, float* __restrict__ out) {
    int j = blockIdx.x * 256 + threadIdx.x;
    if (j >= Ncols) return;
    float s = 0.0f;
    for (int i = 0; i < M; ++i) s += A[(long)i * lda + j] * w[i];
    float base = (add1 ? add1[j] : 0.0f) - (add2 ? add2[j] : 0.0f);
    out[j] = base + sgn * s;
}

// ---------- sc[1] = x.z ; sc[0] = mu ----------
__global__ __launch_bounds__(256) void k_dots_init(const float* __restrict__ x, const float* __restrict__ z,
                                                   float* __restrict__ sc) {
    __shared__ float red[256];
    float s = 0.0f;
    for (int i = threadIdx.x; i < 2485; i += 256) s += x[i] * z[i];
    red[threadIdx.x] = s;
    __syncthreads();
    for (int o = 128; o; o >>= 1) {
        if (threadIdx.x < o) red[threadIdx.x] += red[threadIdx.x + o];
        __syncthreads();
    }
    if (threadIdx.x == 0) { sc[1] = red[0]; sc[0] = red[0] / 70.0f; }
}

// ---------- sc[7] = (x+alpha dx).(z+beta dz) ----------
__global__ __launch_bounds__(256) void k_dot_new(const float* __restrict__ x, const float* __restrict__ dx,
                                                 const float* __restrict__ z, const float* __restrict__ dz,
                                                 float* __restrict__ sc) {
    __shared__ float red[256];
    float a = sc[2], b = sc[3];
    float s = 0.0f;
    for (int i = threadIdx.x; i < 2485; i += 256)
        s += (x[i] + a * dx[i]) * (z[i] + b * dz[i]);
    red[threadIdx.x] = s;
    __syncthreads();
    for (int o = 128; o; o >>= 1) {
        if (threadIdx.x < o) red[threadIdx.x] += red[threadIdx.x + o];
        __syncthreads();
    }
    if (threadIdx.x == 0) sc[7] = red[0];
}

// ---------- fused Rc chain: W1 = Pu*(X*Z)*Pi ; Rc = -svec_sym(W1) ----------
__global__ __launch_bounds__(256) void k_rc_chain(const float* __restrict__ X, const float* __restrict__ Z,
                                                  const float* __restrict__ Pu, const float* __restrict__ Pi,
                                                  float* __restrict__ W1out, float* __restrict__ Rc) {
    __shared__ float A[70][71], B[70][71], C[70][71];
    int tid = threadIdx.x;
    for (int e = tid; e < 4900; e += 256) { A[e / 70][e % 70] = X[e]; B[e / 70][e % 70] = Z[e]; }
    __syncthreads();
    for (int e = tid; e < 4900; e += 256) {
        int i = e / 70, j = e % 70;
        float s = 0.0f;
        for (int k = 0; k < 70; ++k) s += A[i][k] * B[k][j];
        C[i][j] = s;
    }
    __syncthreads();
    for (int e = tid; e < 4900; e += 256) A[e / 70][e % 70] = Pu[e];
    __syncthreads();
    for (int e = tid; e < 4900; e += 256) {
        int i = e / 70, j = e % 70;
        float s = 0.0f;
        for (int k = 0; k < 70; ++k) s += A[i][k] * C[k][j];
        B[i][j] = s;
    }
    __syncthreads();
    for (int e = tid; e < 4900; e += 256) A[e / 70][e % 70] = Pi[e];
    __syncthreads();
    for (int e = tid; e < 4900; e += 256) {
        int i = e / 70, j = e % 70;
        float s = 0.0f;
        for (int k = 0; k < 70; ++k) s += B[i][k] * A[k][j];
        C[i][j] = s;
        W1out[e] = s;
    }
    __syncthreads();
    for (int t = tid; t < 2485; t += 256) {
        int i, j;
        d_t2ij(t, i, j);
        float v = (i == j) ? C[i][i] : (C[i][j] + C[j][i]) * SQHf;
        Rc[t] = -v;
    }
}

// ---------- fused Rc2 chain: W2 = Pu*(smat(dx)*smat(dz))*Pi ; Rc2 = svec(sigmu*I - sym(W1) - sym(W2)) ----------
__global__ __launch_bounds__(256) void k_rc2_chain(const float* __restrict__ dxv, const float* __restrict__ dzv,
                                                   const float* __restrict__ Pu, const float* __restrict__ Pi,
                                                   const float* __restrict__ W1, const float* __restrict__ sc,
                                                   float* __restrict__ Rc2) {
    __shared__ float A[70][71], B[70][71], C[70][71];
    int tid = threadIdx.x;
    for (int e = tid; e < 4900; e += 256) {
        int i = e / 70, j = e % 70;
        int hi = i > j ? i : j, lo = i > j ? j : i;
        float vx = dxv[(hi * (hi + 1)) / 2 + lo];
        float vz = dzv[(hi * (hi + 1)) / 2 + lo];
        A[i][j] = (i == j) ? vx : vx * SQHf;
        B[i][j] = (i == j) ? vz : vz * SQHf;
    }
    __syncthreads();
    for (int e = tid; e < 4900; e += 256) {
        int i = e / 70, j = e % 70;
        float s = 0.0f;
        for (int k = 0; k < 70; ++k) s += A[i][k] * B[k][j];
        C[i][j] = s;
    }
    __syncthreads();
    for (int e = tid; e < 4900; e += 256) A[e / 70][e % 70] = Pu[e];
    __syncthreads();
    for (int e = tid; e < 4900; e += 256) {
        int i = e / 70, j = e % 70;
        float s = 0.0f;
        for (int k = 0; k < 70; ++k) s += A[i][k] * C[k][j];
        B[i][j] = s;
    }
    __syncthreads();
    for (int e = tid; e < 4900; e += 256) A[e / 70][e % 70] = Pi[e];
    __syncthreads();
    for (int e = tid; e < 4900; e += 256) {
        int i = e / 70, j = e % 70;
        float s = 0.0f;
        for (int k = 0; k < 70; ++k) s += B[i][k] * A[k][j];
        C[i][j] = s;
    }
    __syncthreads();
    float sm = sc[13];
    for (int t = tid; t < 2485; t += 256) {
        int i, j;
        d_t2ij(t, i, j);
        if (i == j)
            Rc2[t] = sm - W1[i * 70 + i] - C[i][i];
        else
            Rc2[t] = -(W1[i * 70 + j] + W1[j * 70 + i] + C[i][j] + C[j][i]) * SQHf;
    }
}

// ---------- skmult: block l -> out row l = svec_sym(K*smat(a_l)*G^T) ----------
__global__ __launch_bounds__(256) void k_skmult(const float* __restrict__ K, const float* __restrict__ G,
                                                const float* __restrict__ Arows, long ldA,
                                                float* __restrict__ outT, long ldOut) {
    int l = blockIdx.x;
    const float* a = Arows + (long)l * ldA;
    float* out = outT + (long)l * ldOut;
    __shared__ float S[70][71];
    __shared__ float T1[70][71];
    for (int e = threadIdx.x; e < 4900; e += 256) {
        int i = e / 70, j = e % 70;
        int hi = i > j ? i : j, lo = i > j ? j : i;
        float v = a[(hi * (hi + 1)) / 2 + lo];
        S[i][j] = (i == j) ? v : v * SQHf;
    }
    __syncthreads();
    for (int e = threadIdx.x; e < 4900; e += 256) {
        int i = e / 70, j = e % 70;
        const float* Gr = G + j * 70;
        float s = 0.0f;
        for (int k = 0; k < 70; ++k) s += S[i][k] * Gr[k];
        T1[i][j] = s;
    }
    __syncthreads();
    for (int t = threadIdx.x; t < 2485; t += 256) {
        int i, j;
        d_t2ij(t, i, j);
        const float* Ki = K + i * 70;
        const float* Kj = K + j * 70;
        float wij = 0.0f, wji = 0.0f;
        for (int k = 0; k < 70; ++k) {
            wij += Ki[k] * T1[k][j];
            wji += Kj[k] * T1[k][i];
        }
        out[t] = (i == j) ? wij : (wij + wji) * SQHf;
    }
}

// ---------- tiled fp32 GEMM: C = beta*C + alpha * A * B^T ----------
#define GBM 64
#define GBK 32
__global__ __launch_bounds__(256) void k_gemm_nt(const float* __restrict__ A, long lda,
                                                 const float* __restrict__ B, long ldb,
                                                 float* __restrict__ C, long ldc,
                                                 int M, int N, int Kd,
                                                 float alpha, float beta, int lower_only) {
    int bx = blockIdx.x, by = blockIdx.y;
    int row0 = by * GBM, col0 = bx * GBM;
    if (lower_only && col0 > row0 + GBM - 1) return;
    __shared__ float As[GBM][GBK + 1], Bs[GBM][GBK + 1];
    int tid = threadIdx.x;
    int tx = tid % 16, ty = tid / 16;
    float acc[4][4] = {{0.f}};
    for (int k0 = 0; k0 < Kd; k0 += GBK) {
        for (int e = tid; e < GBM * GBK; e += 256) {
            int r = e / GBK, cc = e % GBK;
            int gr = row0 + r, gc = k0 + cc;
            As[r][cc] = (gr < M && gc < Kd) ? A[(long)gr * lda + gc] : 0.0f;
        }
        for (int e = tid; e < GBM * GBK; e += 256) {
            int r = e / GBK, cc = e % GBK;
            int gr = col0 + r, gc = k0 + cc;
            Bs[r][cc] = (gr < N && gc < Kd) ? B[(long)gr * ldb + gc] : 0.0f;
        }
        __syncthreads();
        for (int kk = 0; kk < GBK; ++kk) {
            float av[4], bv[4];
#pragma unroll
            for (int m = 0; m < 4; ++m) av[m] = As[ty * 4 + m][kk];
#pragma unroll
            for (int n = 0; n < 4; ++n) bv[n] = Bs[tx * 4 + n][kk];
#pragma unroll
            for (int m = 0; m < 4; ++m)
#pragma unroll
                for (int n = 0; n < 4; ++n) acc[m][n] += av[m] * bv[n];
        }
        __syncthreads();
    }
#pragma unroll
    for (int m = 0; m < 4; ++m)
#pragma unroll
        for (int n = 0; n < 4; ++n) {
            int gr = row0 + ty * 4 + m, gc = col0 + tx * 4 + n;
            if (gr < M && gc < N) {
                float* cp = &C[(long)gr * ldc + gc];
                if (beta != 0.0f) *cp = beta * (*cp) + alpha * acc[m][n];
                else *cp = alpha * acc[m][n];
            }
        }
}

// ---------- blocked Cholesky: diag factor + L11 inverse ----------
__global__ __launch_bounds__(256) void k_chol_diag_inv(float* __restrict__ Mp, long ld, int jb, int nb,
                                                       float* __restrict__ Linv) {
    __shared__ float S[64][65];
    __shared__ float V[64][65];
    int tid = threadIdx.x;
    for (int e = tid; e < nb * nb; e += 256) S[e / nb][e % nb] = Mp[(long)(jb + e / nb) * ld + jb + e % nb];
    __syncthreads();
    for (int k = 0; k < nb; ++k) {
        if (tid == 0) S[k][k] = sqrtf(S[k][k]);
        __syncthreads();
        float d = S[k][k];
        for (int i = k + 1 + tid; i < nb; i += 256) S[i][k] /= d;
        __syncthreads();
        for (int e = tid; e < nb * nb; e += 256) {
            int i = e / nb, j = e % nb;
            if (j > k && i >= j) S[i][j] -= S[i][k] * S[j][k];
        }
        __syncthreads();
    }
    for (int e = tid; e < nb * nb; e += 256) {
        int i = e / nb, j = e % nb;
        if (i >= j) Mp[(long)(jb + i) * ld + jb + j] = S[i][j];
    }
    // lower-triangular inverse, column-parallel
    if (tid < nb) {
        int c = tid;
        V[c][c] = 1.0f / S[c][c];
        for (int i = c + 1; i < nb; ++i) {
            float s = 0.0f;
            for (int k = c; k < i; ++k) s += S[i][k] * V[k][c];
            V[i][c] = -s / S[i][i];
        }
    }
    __syncthreads();
    for (int e = tid; e < 4096; e += 256) {
        int i = e >> 6, j = e & 63;
        Linv[e] = (i < nb && j < nb && i >= j) ? V[i][j] : 0.0f;
    }
}

// ---------- panel: A21 <- A21 * Linv^T (parallel GEMM, no serial solve) ----------
__global__ __launch_bounds__(256) void k_panel_trsm(float* __restrict__ Mp, long ld, int jb, int nb, int n,
                                                    const float* __restrict__ Linv) {
    __shared__ float Vs[64][65];
    __shared__ float As[64][65];
    int r0 = jb + nb + blockIdx.x * 64;
    int nrows = n - r0;
    if (nrows > 64) nrows = 64;
    if (nrows <= 0) return;
    int tid = threadIdx.x;
    for (int e = tid; e < 4096; e += 256) { int i = e >> 6, j = e & 63; Vs[i][j] = Linv[e]; }
    for (int e = tid; e < nrows * nb; e += 256) {
        int i = e / nb, j = e % nb;
        As[i][j] = Mp[(long)(r0 + i) * ld + jb + j];
    }
    __syncthreads();
    int tx = tid % 16, ty = tid / 16;
    float acc[4][4] = {{0.f}};
    for (int k = 0; k < nb; ++k) {
        float av[4], bv[4];
#pragma unroll
        for (int m = 0; m < 4; ++m) av[m] = As[ty * 4 + m][k];
#pragma unroll
        for (int c = 0; c < 4; ++c) bv[c] = Vs[tx * 4 + c][k];
#pragma unroll
        for (int m = 0; m < 4; ++m)
#pragma unroll
            for (int c = 0; c < 4; ++c) acc[m][c] += av[m] * bv[c];
    }
#pragma unroll
    for (int m = 0; m < 4; ++m)
#pragma unroll
        for (int c = 0; c < 4; ++c) {
            int gr = ty * 4 + m, gc = tx * 4 + c;
            if (gr < nrows && gc < nb) Mp[(long)(r0 + gr) * ld + jb + gc] = acc[m][c];
        }
}

// ---------- SPD solve with precomputed diag-block inverses ----------
__global__ __launch_bounds__(1024) void k_spdsolve2(const float* __restrict__ L, long ld, int n,
                                                    const float* __restrict__ Linv,
                                                    const float* __restrict__ bin, float* __restrict__ xout) {
    __shared__ float bv[2048];
    __shared__ float yt[64];
    int tid = threadIdx.x;
    for (int i = tid; i < n; i += 1024) bv[i] = bin[i];
    __syncthreads();
    int nblk = (n + 63) / 64;
    int r = tid >> 4, l = tid & 15;
    // forward: L y = b
    for (int t = 0; t < nblk; ++t) {
        int jb = t * 64;
        int nb = n - jb < 64 ? n - jb : 64;
        const float* Vi = Linv + (long)t * 4096;
        float s = 0.0f;
        if (r < nb) {
            for (int c = l; c < nb; c += 16) s += Vi[r * 64 + c] * bv[jb + c];
        }
        s += __shfl_down(s, 8, 16);
        s += __shfl_down(s, 4, 16);
        s += __shfl_down(s, 2, 16);
        s += __shfl_down(s, 1, 16);
        if (l == 0 && r < 64) yt[r] = s;
        __syncthreads();
        for (int i = tid; i < nb; i += 1024) bv[jb + i] = yt[i];
        __syncthreads();
        for (int i = jb + nb + tid; i < n; i += 1024) {
            const float* Lr = L + (long)i * ld + jb;
            float acc = 0.0f;
            if (nb == 64) {
                const float4* L4 = (const float4*)Lr;
#pragma unroll
                for (int m = 0; m < 16; ++m) {
                    float4 q = L4[m];
                    acc += q.x * bv[jb + 4 * m] + q.y * bv[jb + 4 * m + 1] + q.z * bv[jb + 4 * m + 2] + q.w * bv[jb + 4 * m + 3];
                }
            } else {
                for (int m = 0; m < nb; ++m) acc += Lr[m] * bv[jb + m];
            }
            bv[i] -= acc;
        }
        __syncthreads();
    }
    // backward: L^T x = y
    for (int t = nblk - 1; t >= 0; --t) {
        int jb = t * 64;
        int nb = n - jb < 64 ? n - jb : 64;
        const float* Vi = Linv + (long)t * 4096;
        float s = 0.0f;
        if (r < nb) {
            for (int c = l; c < nb; c += 16) s += Vi[c * 64 + r] * bv[jb + c];  // Linv^T
        }
        s += __shfl_down(s, 8, 16);
        s += __shfl_down(s, 4, 16);
        s += __shfl_down(s, 2, 16);
        s += __shfl_down(s, 1, 16);
        if (l == 0 && r < 64) yt[r] = s;
        __syncthreads();
        for (int i = tid; i < nb; i += 1024) bv[jb + i] = yt[i];
        __syncthreads();
        for (int i = tid; i < jb; i += 1024) {
            float acc = 0.0f;
            for (int m = 0; m < nb; ++m) acc += L[(long)(jb + m) * ld + i] * bv[jb + m];
            bv[i] -= acc;
        }
        __syncthreads();
    }
    for (int i = tid; i < n; i += 1024) xout[i] = bv[i];
}

// ---------- fused step-length: E = op(R)^T smat(v) op(R), Jacobi eig, lambda_min -> sc[outi] ----------
__device__ __forceinline__ int jac_f(int i, int r) {
    return (i == 0) ? 0 : 1 + ((i - 1 + r) % 69);
}
__global__ __launch_bounds__(256) void k_steplen_eig(const float* __restrict__ dxv, const float* __restrict__ dzv,
                                                     const float* __restrict__ Qi, const float* __restrict__ Pi,
                                                     float* __restrict__ sc, int o0, int o1) {
    const float* v = blockIdx.x ? dzv : dxv;
    const float* Rm = blockIdx.x ? Pi : Qi;
    int outi = blockIdx.x ? o1 : o0;
    __shared__ float S[70][71], T[70][71], A[70][71];
    __shared__ float cs[35], sn[35];
    int tid = threadIdx.x;
    for (int e = tid; e < 4900; e += 256) {
        int i = e / 70, j = e % 70;
        int hi = i > j ? i : j, lo = i > j ? j : i;
        float val = v[(hi * (hi + 1)) / 2 + lo];
        S[i][j] = (i == j) ? val : val * SQHf;
        A[i][j] = Rm[e];
    }
    __syncthreads();
    // T = A^T * S
    for (int e = tid; e < 4900; e += 256) {
        int i = e / 70, j = e % 70;
        float s = 0.0f;
        for (int k = 0; k < 70; ++k) s += A[k][i] * S[k][j];
        T[i][j] = s;
    }
    __syncthreads();
    // S = T * A   (E matrix, Jacobi operates in-place on S)
    for (int e = tid; e < 4900; e += 256) {
        int i = e / 70, j = e % 70;
        float s = 0.0f;
        for (int k = 0; k < 70; ++k) s += T[i][k] * A[k][j];
        S[i][j] = s;
    }
    __syncthreads();
    // parallel cyclic Jacobi, fused 2x2 tile application (2 barriers/round)
    for (int sw = 0; sw < 6; ++sw) {
        for (int rr = 0; rr < 69; ++rr) {
            if (tid < 35) {
                int p = jac_f(tid, rr), q = jac_f(69 - tid, rr);
                float app = S[p][p], aqq = S[q][q], apq = S[p][q];
                float cc = 1.0f, ss = 0.0f;
                float denom = fabsf(app) + fabsf(aqq);
                if (fabsf(apq) > 1e-12f * denom + 1e-30f) {
                    float tau = (aqq - app) / (2.0f * apq);
                    float t = ((tau >= 0.0f) ? 1.0f : -1.0f) / (fabsf(tau) + sqrtf(1.0f + tau * tau));
                    cc = 1.0f / sqrtf(1.0f + t * t);
                    ss = t * cc;
                }
                cs[tid] = cc;
                sn[tid] = ss;
            }
            __syncthreads();
            for (int t = tid; t < 1225; t += 256) {
                int a = t / 35, b = t - a * 35;
                int pa = jac_f(a, rr), qa = jac_f(69 - a, rr);
                int pb = jac_f(b, rr), qb = jac_f(69 - b, rr);
                float ca = cs[a], sa = sn[a], cb = cs[b], sb = sn[b];
                float m00 = S[pa][pb], m01 = S[pa][qb], m10 = S[qa][pb], m11 = S[qa][qb];
                float r00 = ca * m00 - sa * m10, r01 = ca * m01 - sa * m11;
                float r10 = sa * m00 + ca * m10, r11 = sa * m01 + ca * m11;
                S[pa][pb] = cb * r00 - sb * r01;
                S[pa][qb] = sb * r00 + cb * r01;
                S[qa][pb] = cb * r10 - sb * r11;
                S[qa][qb] = sb * r10 + cb * r11;
            }
            __syncthreads();
        }
    }
    __shared__ float red[256];
    float mn = 1e30f;
    for (int i = tid; i < 70; i += 256) mn = fminf(mn, S[i][i]);
    red[tid] = mn;
    __syncthreads();
    for (int o = 128; o; o >>= 1) {
        if (tid < o) red[tid] = fminf(red[tid], red[tid + o]);
        __syncthreads();
    }
    if (tid == 0) sc[outi] = red[0];
}

// ---------- scalar kernels ----------
__global__ void k_pred_scalars(float* sc) {
    float l0a = sc[11], l0b = sc[12];
    float sa = (l0a < 0.0f) ? -1.0f / l0a : 20.0f;
    float sb = (l0b < 0.0f) ? -1.0f / l0b : 20.0f;
    float alpha = fminf(0.5f, 0.9f * sa);
    float beta = fminf(0.5f, 0.9f * sb);
    float minab = fminf(alpha, beta);
    sc[2] = alpha;
    sc[3] = beta;
    sc[4] = minab;
    float mu = sc[0];
    sc[5] = (mu > 1e-6f && minab >= 0.57735026918962576f) ? fmaxf(1.0f, 3.0f * minab * minab) : 1.0f;
}
__global__ void k_sigma(float* sc) {
    float dn = sc[7], xz = sc[1], e = sc[5];
    float frac = dn / xz;
    float fs = (dn < 0.0f) ? 1.0f : frac;
    float sig = (dn < 0.0f) ? 0.8f : fminf(1.0f, powf(fs, e));
    sc[6] = sig;
    sc[13] = sig * sc[0];
    sc[8] = 0.9f + 0.09f * sc[4];
}
__global__ void k_corr_scalars(float* sc) {
    float g2 = sc[8];
    float l0a = sc[14], l0b = sc[15];
    float sa = (l0a < 0.0f) ? -1.0f / l0a : 20.0f;
    float sb = (l0b < 0.0f) ? -1.0f / l0b : 20.0f;
    sc[9] = fminf(0.5f, g2 * sa);
    sc[10] = fminf(0.5f, g2 * sb);
}

// ---------- out = a*u + b*v ----------
__global__ void k_axpby(const float* __restrict__ u, const float* __restrict__ v,
                        float a, float b, float* __restrict__ out, int n) {
    int i = blockIdx.x * 256 + threadIdx.x;
    if (i < n) out[i] = a * u[i] + b * v[i];
}

// ---------- final outputs ----------
__global__ void k_final(const float* __restrict__ x, const float* __restrict__ y, const float* __restrict__ z,
                        const float* __restrict__ dx2, const float* __restrict__ dy2, const float* __restrict__ dz2,
                        const float* __restrict__ normc, const float* __restrict__ sc, float* __restrict__ out) {
    int i = blockIdx.x * 256 + threadIdx.x;
    float a2 = sc[9], b2 = sc[10];
    if (i < 2485) out[i] = x[i] + a2 * dx2[i];
    else if (i < 4485) { int j = i - 2485; out[i] = y[j] + b2 * dy2[j]; }
    else if (i < 6970) { int j = i - 4485; out[i] = z[j] + b2 * dz2[j]; }
    else if (i < 8970) { int j = i - 6970; out[i] = (y[j] + b2 * dy2[j]) * normc[0]; }
}

extern "C" void kernel_launch(void* const* d_in, const int* in_sizes, int n_in,
                              void* d_out, int out_size, void* d_ws, size_t ws_size,
                              hipStream_t stream) {
    const float* x = (const float*)d_in[0];
    const float* y = (const float*)d_in[1];
    const float* z = (const float*)d_in[2];
    const float* A = (const float*)d_in[3];
    const float* b = (const float*)d_in[4];
    const float* c = (const float*)d_in[5];
    const float* normc = (const float*)d_in[6];
    float* out = (float*)d_out;
    float* ws = (float*)d_ws;

    float* SKT = ws;                       // 2000 x 2485
    float* Mm = ws + 4970000;              // 2000 x 2000
    float* S0 = ws + 8970000;
    float* X = S0;
    float* Z = S0 + 4900;
    float* Qu = S0 + 9800;
    float* Pu = S0 + 14700;
    float* Qi = S0 + 19600;
    float* Pi = S0 + 24500;
    float* Zi = S0 + 29400;
    float* W1 = S0 + 44100;
    float* rp = S0 + 83300;
    float* h = S0 + 85300;
    float* dy = S0 + 87300;
    float* dy2 = S0 + 89300;
    float* h2 = S0 + 91300;
    float* Rd = S0 + 93300;
    float* Rc = S0 + 95785;
    float* k1 = S0 + 98270;
    float* k2 = S0 + 100755;
    float* dz = S0 + 103240;
    float* dx = S0 + 105725;
    float* Rc2 = S0 + 108210;
    float* k2b = S0 + 110695;
    float* dz2 = S0 + 113180;
    float* dx2 = S0 + 115665;
    float* tmpv = S0 + 118150;
    float* sc = S0 + 120635;
    float* Linv = S0 + 121000;             // 32 slots x 4096 = 131072 floats

    // ---- setup: X, Z, factors, inverses ----
    k_smat2<<<39, 256, 0, stream>>>(x, X, z, Z);
    k_chol2<<<2, 256, 0, stream>>>(X, Qu, Z, Pu);
    k_trinv2<<<2, 256, 0, stream>>>(Qu, Qi, Pu, Pi);
    k_mm70<<<1, 256, 0, stream>>>(Pi, 0, Pi, 1, Zi);   // Zinv = Pinv * Pinv^T

    // ---- residuals & mu ----
    k_gemv_rowA<<<2000, 256, 0, stream>>>(A, 2485L, 2485, x, b, -1.0f, rp);
    k_gemv_colAT<<<10, 256, 0, stream>>>(A, 2485L, 2000, 2485, y, c, z, -1.0f, Rd);
    k_dots_init<<<1, 256, 0, stream>>>(x, z, sc);

    // ---- Rc (fused chain) ----
    k_rc_chain<<<1, 256, 0, stream>>>(X, Z, Pu, Pi, W1, Rc);

    // ---- SKT ; Mmat = A * SKT^T (lower) ----
    k_skmult<<<2000, 256, 0, stream>>>(X, Zi, A, 2485L, SKT, 2485L);
    k_gemm_nt<<<dim3(32, 32), 256, 0, stream>>>(A, 2485L, SKT, 2485L, Mm, 2000L,
                                                2000, 2000, 2485, 1.0f, 0.0f, 1);

    // ---- Cholesky of Mmat (blocked, parallel panel via diag inverse) ----
    for (int jb = 0; jb < 2000; jb += 64) {
        int nb = (2000 - jb) < 64 ? (2000 - jb) : 64;
        float* Lslot = Linv + (long)(jb / 64) * 4096;
        k_chol_diag_inv<<<1, 256, 0, stream>>>(Mm, 2000L, jb, nb, Lslot);
        int rows = 2000 - jb - nb;
        if (rows > 0) {
            int gb = (rows + 63) / 64;
            k_panel_trsm<<<gb, 256, 0, stream>>>(Mm, 2000L, jb, nb, 2000, Lslot);
            const float* pan = Mm + (size_t)(jb + nb) * 2000 + jb;
            float* csub = Mm + (size_t)(jb + nb) * 2000 + (jb + nb);
            k_gemm_nt<<<dim3(gb, gb), 256, 0, stream>>>(pan, 2000L, pan, 2000L, csub, 2000L,
                                                        rows, rows, nb, -1.0f, 1.0f, 1);
        }
    }

    // ---- predictor ----
    k_skmult<<<1, 256, 0, stream>>>(X, Zi, Rd, 0L, k1, 0L);
    k_skmult<<<1, 256, 0, stream>>>(Pi, Pi, Rc, 0L, k2, 0L);
    k_axpby<<<10, 256, 0, stream>>>(k1, k2, 1.0f, -1.0f, tmpv, 2485);
    k_gemv_rowA<<<2000, 256, 0, stream>>>(A, 2485L, 2485, tmpv, rp, 1.0f, h);
    k_spdsolve2<<<1, 1024, 0, stream>>>(Mm, 2000L, 2000, Linv, h, dy);
    k_gemv_colAT<<<10, 256, 0, stream>>>(A, 2485L, 2000, 2485, dy, Rd, (const float*)0, -1.0f, dz);
    k_skmult<<<1, 256, 0, stream>>>(X, Zi, dz, 0L, tmpv, 0L);
    k_axpby<<<10, 256, 0, stream>>>(x, tmpv, -1.0f, -1.0f, dx, 2485);

    // ---- predictor step lengths (fused smat+sandwich+Jacobi) ----
    k_steplen_eig<<<2, 256, 0, stream>>>(dx, dz, Qi, Pi, sc, 11, 12);
    k_pred_scalars<<<1, 1, 0, stream>>>(sc);
    k_dot_new<<<1, 256, 0, stream>>>(x, dx, z, dz, sc);
    k_sigma<<<1, 1, 0, stream>>>(sc);

    // ---- corrector RHS (fused chain) ----
    k_rc2_chain<<<1, 256, 0, stream>>>(dx, dz, Pu, Pi, W1, sc, Rc2);
    k_skmult<<<1, 256, 0, stream>>>(Pi, Pi, Rc2, 0L, k2b, 0L);
    k_axpby<<<10, 256, 0, stream>>>(k1, k2b, 1.0f, -1.0f, tmpv, 2485);
    k_gemv_rowA<<<2000, 256, 0, stream>>>(A, 2485L, 2485, tmpv, rp, 1.0f, h2);
    k_spdsolve2<<<1, 1024, 0, stream>>>(Mm, 2000L, 2000, Linv, h2, dy2);
    k_gemv_colAT<<<10, 256, 0, stream>>>(A, 2485L, 2000, 2485, dy2, Rd, (const float*)0, -1.0f, dz2);
    k_skmult<<<1, 256, 0, stream>>>(X, Zi, dz2, 0L, tmpv, 0L);
    k_axpby<<<10, 256, 0, stream>>>(k2b, tmpv, 1.0f, -1.0f, dx2, 2485);

    // ---- corrector step lengths ----
    k_steplen_eig<<<2, 256, 0, stream>>>(dx2, dz2, Qi, Pi, sc, 14, 15);
    k_corr_scalars<<<1, 1, 0, stream>>>(sc);

    // ---- outputs ----
    k_final<<<36, 256, 0, stream>>>(x, y, z, dx2, dy2, dz2, normc, sc, out);
}

// Round 6
// 10308.649 us; speedup vs baseline: 1.6945x; 1.2298x over previous
//
#include <hip/hip_runtime.h>
#include <math.h>

#define SQHf 0.70710678118654752440f

struct Pairs16 { int4 q[16]; };

__device__ __forceinline__ void d_t2ij(int t, int& i, int& j) {
    float f = sqrtf(8.0f * (float)t + 1.0f);
    int r = (int)((f - 1.0f) * 0.5f);
    while (((r + 1) * (r + 2)) / 2 <= t) ++r;
    while ((r * (r + 1)) / 2 > t) --r;
    i = r;
    j = t - (r * (r + 1)) / 2;
}

// ---------- build two smat matrices from svec vectors ----------
__global__ void k_smat2(const float* __restrict__ v1, float* __restrict__ M1,
                        const float* __restrict__ v2, float* __restrict__ M2) {
    int idx = blockIdx.x * 256 + threadIdx.x;
    if (idx >= 9800) return;
    int which = idx / 4900;
    int e = idx - which * 4900;
    const float* v = which ? v2 : v1;
    float* M = which ? M2 : M1;
    int i = e / 70, j = e % 70;
    int hi = i > j ? i : j, lo = i > j ? j : i;
    float val = v[(hi * (hi + 1)) / 2 + lo];
    M[e] = (i == j) ? val : val * SQHf;
}

// ---------- Cholesky of two 70x70 SPD matrices -> upper factors R ----------
__global__ __launch_bounds__(256) void k_chol2(const float* __restrict__ A0, float* __restrict__ R0,
                                               const float* __restrict__ A1, float* __restrict__ R1) {
    const float* A = blockIdx.x ? A1 : A0;
    float* R = blockIdx.x ? R1 : R0;
    __shared__ float S[70][71];
    for (int e = threadIdx.x; e < 4900; e += 256) S[e / 70][e % 70] = A[e];
    __syncthreads();
    for (int k = 0; k < 70; ++k) {
        if (threadIdx.x == 0) S[k][k] = sqrtf(S[k][k]);
        __syncthreads();
        float d = S[k][k];
        for (int i = k + 1 + threadIdx.x; i < 70; i += 256) S[i][k] /= d;
        __syncthreads();
        for (int e = threadIdx.x; e < 4900; e += 256) {
            int i = e / 70, j = e % 70;
            if (j > k && i >= j) S[i][j] -= S[i][k] * S[j][k];
        }
        __syncthreads();
    }
    for (int e = threadIdx.x; e < 4900; e += 256) {
        int i = e / 70, j = e % 70;
        R[e] = (i <= j) ? S[j][i] : 0.0f;
    }
}

// ---------- inverse of two upper-triangular 70x70 ----------
__global__ __launch_bounds__(256) void k_trinv2(const float* __restrict__ R0, float* __restrict__ O0,
                                                const float* __restrict__ R1, float* __restrict__ O1) {
    const float* R = blockIdx.x ? R1 : R0;
    float* O = blockIdx.x ? O1 : O0;
    __shared__ float S[70][71];
    __shared__ float V[70][71];
    for (int e = threadIdx.x; e < 4900; e += 256) S[e / 70][e % 70] = R[e];
    __syncthreads();
    int j = threadIdx.x;
    if (j < 70) {
        for (int i = j; i >= 0; --i) {
            float s = (i == j) ? 1.0f : 0.0f;
            for (int k = i + 1; k <= j; ++k) s -= S[i][k] * V[j][k];
            V[j][i] = s / S[i][i];
        }
    }
    __syncthreads();
    for (int e = threadIdx.x; e < 4900; e += 256) {
        int i = e / 70, jj = e % 70;
        O[e] = (i <= jj) ? V[jj][i] : 0.0f;
    }
}

// ---------- generic 70x70 matmul ----------
__global__ __launch_bounds__(256) void k_mm70(const float* __restrict__ A, int tA,
                                              const float* __restrict__ B, int tB,
                                              float* __restrict__ C) {
    __shared__ float As[70][71], Bs[70][71];
    for (int e = threadIdx.x; e < 4900; e += 256) {
        int i = e / 70, j = e % 70;
        As[i][j] = tA ? A[j * 70 + i] : A[e];
        Bs[i][j] = tB ? B[j * 70 + i] : B[e];
    }
    __syncthreads();
    for (int e = threadIdx.x; e < 4900; e += 256) {
        int i = e / 70, j = e % 70;
        float s = 0.0f;
        for (int k = 0; k < 70; ++k) s += As[i][k] * Bs[k][j];
        C[e] = s;
    }
}

// ---------- GEMV with A row-major ----------
__global__ __launch_bounds__(256) void k_gemv_rowA(const float* __restrict__ A, long lda, int Kdim,
                                                   const float* __restrict__ v, const float* __restrict__ add,
                                                   float sgn, float* __restrict__ out) {
    int row = blockIdx.x;
    const float* Ar = A + (long)row * lda;
    float s = 0.0f;
    for (int k = threadIdx.x; k < Kdim; k += 256) s += Ar[k] * v[k];
    __shared__ float red[256];
    red[threadIdx.x] = s;
    __syncthreads();
    for (int o = 128; o; o >>= 1) {
        if (threadIdx.x < o) red[threadIdx.x] += red[threadIdx.x + o];
        __syncthreads();
    }
    if (threadIdx.x == 0) out[row] = (add ? add[row] : 0.0f) + sgn * red[0];
}

// ---------- A^T w partials: grid (xblk, S) over 2000 rows ----------
__global__ __launch_bounds__(256) void k_colAT_part(const float* __restrict__ A, long lda, int M, int Ncols,
                                                    const float* __restrict__ w, float* __restrict__ partial) {
    int j = blockIdx.x * 256 + threadIdx.x;
    int s = blockIdx.y;
    int rpb = (M + gridDim.y - 1) / gridDim.y;
    int i0 = s * rpb, i1 = i0 + rpb < M ? i0 + rpb : M;
    float acc = 0.0f;
    if (j < Ncols)
        for (int i = i0; i < i1; ++i) acc += A[(long)i * lda + j] * w[i];
    if (j < Ncols) partial[(long)s * Ncols + j] = acc;
}
__global__ __launch_bounds__(256) void k_colAT_fin(const float* __restrict__ partial, int S, int Ncols,
                                                   const float* __restrict__ add1, const float* __restrict__ add2,
                                                   float sgn, float* __restrict__ out) {
    int j = blockIdx.x * 256 + threadIdx.x;
    if (j >= Ncols) return;
    float s = 0.0f;
    for (int k = 0; k < S; ++k) s += partial[(long)k * Ncols + j];
    float base = (add1 ? add1[j] : 0.0f) - (add2 ? add2[j] : 0.0f);
    out[j] = base + sgn * s;
}

// ---------- sc[1] = x.z ; sc[0] = mu ----------
__global__ __launch_bounds__(256) void k_dots_init(const float* __restrict__ x, const float* __restrict__ z,
                                                   float* __restrict__ sc) {
    __shared__ float red[256];
    float s = 0.0f;
    for (int i = threadIdx.x; i < 2485; i += 256) s += x[i] * z[i];
    red[threadIdx.x] = s;
    __syncthreads();
    for (int o = 128; o; o >>= 1) {
        if (threadIdx.x < o) red[threadIdx.x] += red[threadIdx.x + o];
        __syncthreads();
    }
    if (threadIdx.x == 0) { sc[1] = red[0]; sc[0] = red[0] / 70.0f; }
}

// ---------- sc[7] = (x+alpha dx).(z+beta dz) ----------
__global__ __launch_bounds__(256) void k_dot_new(const float* __restrict__ x, const float* __restrict__ dx,
                                                 const float* __restrict__ z, const float* __restrict__ dz,
                                                 float* __restrict__ sc) {
    __shared__ float red[256];
    float a = sc[2], b = sc[3];
    float s = 0.0f;
    for (int i = threadIdx.x; i < 2485; i += 256)
        s += (x[i] + a * dx[i]) * (z[i] + b * dz[i]);
    red[threadIdx.x] = s;
    __syncthreads();
    for (int o = 128; o; o >>= 1) {
        if (threadIdx.x < o) red[threadIdx.x] += red[threadIdx.x + o];
        __syncthreads();
    }
    if (threadIdx.x == 0) sc[7] = red[0];
}

// ---------- fused Rc chain ----------
__global__ __launch_bounds__(256) void k_rc_chain(const float* __restrict__ X, const float* __restrict__ Z,
                                                  const float* __restrict__ Pu, const float* __restrict__ Pi,
                                                  float* __restrict__ W1out, float* __restrict__ Rc) {
    __shared__ float A[70][71], B[70][71], C[70][71];
    int tid = threadIdx.x;
    for (int e = tid; e < 4900; e += 256) { A[e / 70][e % 70] = X[e]; B[e / 70][e % 70] = Z[e]; }
    __syncthreads();
    for (int e = tid; e < 4900; e += 256) {
        int i = e / 70, j = e % 70;
        float s = 0.0f;
        for (int k = 0; k < 70; ++k) s += A[i][k] * B[k][j];
        C[i][j] = s;
    }
    __syncthreads();
    for (int e = tid; e < 4900; e += 256) A[e / 70][e % 70] = Pu[e];
    __syncthreads();
    for (int e = tid; e < 4900; e += 256) {
        int i = e / 70, j = e % 70;
        float s = 0.0f;
        for (int k = 0; k < 70; ++k) s += A[i][k] * C[k][j];
        B[i][j] = s;
    }
    __syncthreads();
    for (int e = tid; e < 4900; e += 256) A[e / 70][e % 70] = Pi[e];
    __syncthreads();
    for (int e = tid; e < 4900; e += 256) {
        int i = e / 70, j = e % 70;
        float s = 0.0f;
        for (int k = 0; k < 70; ++k) s += B[i][k] * A[k][j];
        C[i][j] = s;
        W1out[e] = s;
    }
    __syncthreads();
    for (int t = tid; t < 2485; t += 256) {
        int i, j;
        d_t2ij(t, i, j);
        float v = (i == j) ? C[i][i] : (C[i][j] + C[j][i]) * SQHf;
        Rc[t] = -v;
    }
}

// ---------- fused Rc2 chain ----------
__global__ __launch_bounds__(256) void k_rc2_chain(const float* __restrict__ dxv, const float* __restrict__ dzv,
                                                   const float* __restrict__ Pu, const float* __restrict__ Pi,
                                                   const float* __restrict__ W1, const float* __restrict__ sc,
                                                   float* __restrict__ Rc2) {
    __shared__ float A[70][71], B[70][71], C[70][71];
    int tid = threadIdx.x;
    for (int e = tid; e < 4900; e += 256) {
        int i = e / 70, j = e % 70;
        int hi = i > j ? i : j, lo = i > j ? j : i;
        float vx = dxv[(hi * (hi + 1)) / 2 + lo];
        float vz = dzv[(hi * (hi + 1)) / 2 + lo];
        A[i][j] = (i == j) ? vx : vx * SQHf;
        B[i][j] = (i == j) ? vz : vz * SQHf;
    }
    __syncthreads();
    for (int e = tid; e < 4900; e += 256) {
        int i = e / 70, j = e % 70;
        float s = 0.0f;
        for (int k = 0; k < 70; ++k) s += A[i][k] * B[k][j];
        C[i][j] = s;
    }
    __syncthreads();
    for (int e = tid; e < 4900; e += 256) A[e / 70][e % 70] = Pu[e];
    __syncthreads();
    for (int e = tid; e < 4900; e += 256) {
        int i = e / 70, j = e % 70;
        float s = 0.0f;
        for (int k = 0; k < 70; ++k) s += A[i][k] * C[k][j];
        B[i][j] = s;
    }
    __syncthreads();
    for (int e = tid; e < 4900; e += 256) A[e / 70][e % 70] = Pi[e];
    __syncthreads();
    for (int e = tid; e < 4900; e += 256) {
        int i = e / 70, j = e % 70;
        float s = 0.0f;
        for (int k = 0; k < 70; ++k) s += B[i][k] * A[k][j];
        C[i][j] = s;
    }
    __syncthreads();
    float sm = sc[13];
    for (int t = tid; t < 2485; t += 256) {
        int i, j;
        d_t2ij(t, i, j);
        if (i == j)
            Rc2[t] = sm - W1[i * 70 + i] - C[i][i];
        else
            Rc2[t] = -(W1[i * 70 + j] + W1[j * 70 + i] + C[i][j] + C[j][i]) * SQHf;
    }
}

// ---------- skmult ----------
__global__ __launch_bounds__(256) void k_skmult(const float* __restrict__ K, const float* __restrict__ G,
                                                const float* __restrict__ Arows, long ldA,
                                                float* __restrict__ outT, long ldOut) {
    int l = blockIdx.x;
    const float* a = Arows + (long)l * ldA;
    float* out = outT + (long)l * ldOut;
    __shared__ float S[70][71];
    __shared__ float T1[70][71];
    for (int e = threadIdx.x; e < 4900; e += 256) {
        int i = e / 70, j = e % 70;
        int hi = i > j ? i : j, lo = i > j ? j : i;
        float v = a[(hi * (hi + 1)) / 2 + lo];
        S[i][j] = (i == j) ? v : v * SQHf;
    }
    __syncthreads();
    for (int e = threadIdx.x; e < 4900; e += 256) {
        int i = e / 70, j = e % 70;
        const float* Gr = G + j * 70;
        float s = 0.0f;
        for (int k = 0; k < 70; ++k) s += S[i][k] * Gr[k];
        T1[i][j] = s;
    }
    __syncthreads();
    for (int t = threadIdx.x; t < 2485; t += 256) {
        int i, j;
        d_t2ij(t, i, j);
        const float* Ki = K + i * 70;
        const float* Kj = K + j * 70;
        float wij = 0.0f, wji = 0.0f;
        for (int k = 0; k < 70; ++k) {
            wij += Ki[k] * T1[k][j];
            wji += Kj[k] * T1[k][i];
        }
        out[t] = (i == j) ? wij : (wij + wji) * SQHf;
    }
}

// ---------- tiled fp32 GEMM: C = beta*C + alpha * A * B^T ----------
#define GBM 64
#define GBK 32
__global__ __launch_bounds__(256) void k_gemm_nt(const float* __restrict__ A, long lda,
                                                 const float* __restrict__ B, long ldb,
                                                 float* __restrict__ C, long ldc,
                                                 int M, int N, int Kd,
                                                 float alpha, float beta, int lower_only) {
    int bx = blockIdx.x, by = blockIdx.y;
    int row0 = by * GBM, col0 = bx * GBM;
    if (lower_only && col0 > row0 + GBM - 1) return;
    __shared__ float As[GBM][GBK + 1], Bs[GBM][GBK + 1];
    int tid = threadIdx.x;
    int tx = tid % 16, ty = tid / 16;
    float acc[4][4] = {{0.f}};
    for (int k0 = 0; k0 < Kd; k0 += GBK) {
        for (int e = tid; e < GBM * GBK; e += 256) {
            int r = e / GBK, cc = e % GBK;
            int gr = row0 + r, gc = k0 + cc;
            As[r][cc] = (gr < M && gc < Kd) ? A[(long)gr * lda + gc] : 0.0f;
        }
        for (int e = tid; e < GBM * GBK; e += 256) {
            int r = e / GBK, cc = e % GBK;
            int gr = col0 + r, gc = k0 + cc;
            Bs[r][cc] = (gr < N && gc < Kd) ? B[(long)gr * ldb + gc] : 0.0f;
        }
        __syncthreads();
        for (int kk = 0; kk < GBK; ++kk) {
            float av[4], bv[4];
#pragma unroll
            for (int m = 0; m < 4; ++m) av[m] = As[ty * 4 + m][kk];
#pragma unroll
            for (int n = 0; n < 4; ++n) bv[n] = Bs[tx * 4 + n][kk];
#pragma unroll
            for (int m = 0; m < 4; ++m)
#pragma unroll
                for (int n = 0; n < 4; ++n) acc[m][n] += av[m] * bv[n];
        }
        __syncthreads();
    }
#pragma unroll
    for (int m = 0; m < 4; ++m)
#pragma unroll
        for (int n = 0; n < 4; ++n) {
            int gr = row0 + ty * 4 + m, gc = col0 + tx * 4 + n;
            if (gr < M && gc < N) {
                float* cp = &C[(long)gr * ldc + gc];
                if (beta != 0.0f) *cp = beta * (*cp) + alpha * acc[m][n];
                else *cp = alpha * acc[m][n];
            }
        }
}

// ---------- dense NN GEMM tile body (C = alpha*A*B, beta=0) ----------
__device__ __forceinline__ void gemm_nn_dev(const float* __restrict__ A, long lda,
                                            const float* __restrict__ B, long ldb,
                                            float* __restrict__ C, long ldc,
                                            int M, int N, int K, float alpha) {
    int row0 = blockIdx.y * 64, col0 = blockIdx.x * 64;
    if (row0 >= M || col0 >= N) return;
    __shared__ float As[64][33], Bs[32][65];
    int tid = threadIdx.x;
    int tx = tid % 16, ty = tid / 16;
    float acc[4][4] = {{0.f}};
    for (int k0 = 0; k0 < K; k0 += 32) {
        for (int e = tid; e < 64 * 32; e += 256) {
            int r = e / 32, cc = e % 32;
            As[r][cc] = (row0 + r < M && k0 + cc < K) ? A[(long)(row0 + r) * lda + k0 + cc] : 0.0f;
        }
        for (int e = tid; e < 32 * 64; e += 256) {
            int kk = e / 64, nn = e % 64;
            Bs[kk][nn] = (k0 + kk < K && col0 + nn < N) ? B[(long)(k0 + kk) * ldb + col0 + nn] : 0.0f;
        }
        __syncthreads();
        for (int kk = 0; kk < 32; ++kk) {
            float av[4], bv[4];
#pragma unroll
            for (int m = 0; m < 4; ++m) av[m] = As[ty * 4 + m][kk];
#pragma unroll
            for (int n = 0; n < 4; ++n) bv[n] = Bs[kk][tx * 4 + n];
#pragma unroll
            for (int m = 0; m < 4; ++m)
#pragma unroll
                for (int n = 0; n < 4; ++n) acc[m][n] += av[m] * bv[n];
        }
        __syncthreads();
    }
#pragma unroll
    for (int m = 0; m < 4; ++m)
#pragma unroll
        for (int n = 0; n < 4; ++n) {
            int gr = row0 + ty * 4 + m, gc = col0 + tx * 4 + n;
            if (gr < M && gc < N) C[(long)gr * ldc + gc] = alpha * acc[m][n];
        }
}

// ---------- batched triangular-inverse doubling: phase A tmp = L21*W11 ----------
__global__ __launch_bounds__(256) void k_tri_phaseA(const float* __restrict__ Mm, long ld,
                                                    float* __restrict__ tmp, Pairs16 pl, int np) {
    int z = blockIdx.z;
    if (z >= np) return;
    int p0 = pl.q[z].x, h = pl.q[z].y, n = pl.q[z].z, toff = pl.q[z].w;
    gemm_nn_dev(Mm + (long)(p0 + h) * ld + p0, ld,
                Mm + (long)p0 * ld + p0, ld,
                tmp + toff, h, n - h, h, h, 1.0f);
}
// ---------- phase B: W21 = -W22*tmp (in place over L21) ----------
__global__ __launch_bounds__(256) void k_tri_phaseB(float* __restrict__ Mm, long ld,
                                                    const float* __restrict__ tmp, Pairs16 pl, int np) {
    int z = blockIdx.z;
    if (z >= np) return;
    int p0 = pl.q[z].x, h = pl.q[z].y, n = pl.q[z].z, toff = pl.q[z].w;
    int M = n - h;
    gemm_nn_dev(Mm + (long)(p0 + h) * ld + (p0 + h), ld,
                tmp + toff, h,
                Mm + (long)(p0 + h) * ld + p0, ld, M, h, M, -1.0f);
}

// ---------- zero strictly-upper 64-blocks of Mm ----------
__global__ void k_zero_upper(float* __restrict__ Mm, int n) {
    int row0 = blockIdx.y * 64, col0 = blockIdx.x * 64;
    if (col0 <= row0) return;
    for (int e = threadIdx.x; e < 4096; e += 256) {
        int i = row0 + (e >> 6), j = col0 + (e & 63);
        if (i < n && j < n) Mm[(long)i * n + j] = 0.0f;
    }
}

// ---------- copy diag-block inverses into Mm diag ----------
__global__ void k_copy_diaginv(float* __restrict__ Mm, long ld, int n, const float* __restrict__ Linv) {
    int t = blockIdx.x;
    int jb = t * 64;
    int nb = n - jb < 64 ? n - jb : 64;
    if (nb <= 0) return;
    const float* Vi = Linv + (long)t * 4096;
    for (int e = threadIdx.x; e < nb * nb; e += 256) {
        int i = e / nb, j = e % nb;
        Mm[(long)(jb + i) * ld + jb + j] = Vi[i * 64 + j];
    }
}

// ---------- lower-tri matvec: out[i] = sum_{k<=i} W[i,k] h[k] ----------
__global__ __launch_bounds__(256) void k_trimv_low(const float* __restrict__ W, long ld, int n,
                                                   const float* __restrict__ h, float* __restrict__ out) {
    int i = blockIdx.x;
    const float* Wr = W + (long)i * ld;
    float s = 0.0f;
    for (int k = threadIdx.x; k <= i; k += 256) s += Wr[k] * h[k];
    __shared__ float red[256];
    red[threadIdx.x] = s;
    __syncthreads();
    for (int o = 128; o; o >>= 1) {
        if (threadIdx.x < o) red[threadIdx.x] += red[threadIdx.x + o];
        __syncthreads();
    }
    if (threadIdx.x == 0) out[i] = red[0];
}

// ---------- W^T v partials: out[j] = sum_{i>=j} W[i,j] v[i] ----------
__global__ __launch_bounds__(256) void k_trimvT_part(const float* __restrict__ W, long ld, int n,
                                                     const float* __restrict__ v, float* __restrict__ partial) {
    int j = blockIdx.x * 256 + threadIdx.x;
    int s = blockIdx.y;
    int rpb = (n + gridDim.y - 1) / gridDim.y;
    int i0 = s * rpb, i1 = i0 + rpb < n ? i0 + rpb : n;
    float acc = 0.0f;
    if (j < n) {
        int ist = i0 > j ? i0 : j;
        for (int i = ist; i < i1; ++i) acc += W[(long)i * ld + j] * v[i];
        partial[(long)s * n + j] = acc;
    }
}
__global__ __launch_bounds__(256) void k_part_reduce(const float* __restrict__ partial, int S, int n,
                                                     float* __restrict__ out) {
    int j = blockIdx.x * 256 + threadIdx.x;
    if (j >= n) return;
    float s = 0.0f;
    for (int k = 0; k < S; ++k) s += partial[(long)k * n + j];
    out[j] = s;
}

// ---------- blocked Cholesky: diag factor + L11 inverse ----------
__global__ __launch_bounds__(256) void k_chol_diag_inv(float* __restrict__ Mp, long ld, int jb, int nb,
                                                       float* __restrict__ Linv) {
    __shared__ float S[64][65];
    __shared__ float V[64][65];
    int tid = threadIdx.x;
    for (int e = tid; e < nb * nb; e += 256) S[e / nb][e % nb] = Mp[(long)(jb + e / nb) * ld + jb + e % nb];
    __syncthreads();
    for (int k = 0; k < nb; ++k) {
        if (tid == 0) S[k][k] = sqrtf(S[k][k]);
        __syncthreads();
        float d = S[k][k];
        for (int i = k + 1 + tid; i < nb; i += 256) S[i][k] /= d;
        __syncthreads();
        for (int e = tid; e < nb * nb; e += 256) {
            int i = e / nb, j = e % nb;
            if (j > k && i >= j) S[i][j] -= S[i][k] * S[j][k];
        }
        __syncthreads();
    }
    for (int e = tid; e < nb * nb; e += 256) {
        int i = e / nb, j = e % nb;
        if (i >= j) Mp[(long)(jb + i) * ld + jb + j] = S[i][j];
    }
    if (tid < nb) {
        int c = tid;
        V[c][c] = 1.0f / S[c][c];
        for (int i = c + 1; i < nb; ++i) {
            float s = 0.0f;
            for (int k = c; k < i; ++k) s += S[i][k] * V[k][c];
            V[i][c] = -s / S[i][i];
        }
    }
    __syncthreads();
    for (int e = tid; e < 4096; e += 256) {
        int i = e >> 6, j = e & 63;
        Linv[e] = (i < nb && j < nb && i >= j) ? V[i][j] : 0.0f;
    }
}

// ---------- panel: A21 <- A21 * Linv^T ----------
__global__ __launch_bounds__(256) void k_panel_trsm(float* __restrict__ Mp, long ld, int jb, int nb, int n,
                                                    const float* __restrict__ Linv) {
    __shared__ float Vs[64][65];
    __shared__ float As[64][65];
    int r0 = jb + nb + blockIdx.x * 64;
    int nrows = n - r0;
    if (nrows > 64) nrows = 64;
    if (nrows <= 0) return;
    int tid = threadIdx.x;
    for (int e = tid; e < 4096; e += 256) { int i = e >> 6, j = e & 63; Vs[i][j] = Linv[e]; }
    for (int e = tid; e < nrows * nb; e += 256) {
        int i = e / nb, j = e % nb;
        As[i][j] = Mp[(long)(r0 + i) * ld + jb + j];
    }
    __syncthreads();
    int tx = tid % 16, ty = tid / 16;
    float acc[4][4] = {{0.f}};
    for (int k = 0; k < nb; ++k) {
        float av[4], bv[4];
#pragma unroll
        for (int m = 0; m < 4; ++m) av[m] = As[ty * 4 + m][k];
#pragma unroll
        for (int c = 0; c < 4; ++c) bv[c] = Vs[tx * 4 + c][k];
#pragma unroll
        for (int m = 0; m < 4; ++m)
#pragma unroll
            for (int c = 0; c < 4; ++c) acc[m][c] += av[m] * bv[c];
    }
#pragma unroll
    for (int m = 0; m < 4; ++m)
#pragma unroll
        for (int c = 0; c < 4; ++c) {
            int gr = ty * 4 + m, gc = tx * 4 + c;
            if (gr < nrows && gc < nb) Mp[(long)(r0 + gr) * ld + jb + gc] = acc[m][c];
        }
}

// ---------- fused step-length eig ----------
__device__ __forceinline__ int jac_f(int i, int r) {
    return (i == 0) ? 0 : 1 + ((i - 1 + r) % 69);
}
__global__ __launch_bounds__(256) void k_steplen_eig(const float* __restrict__ dxv, const float* __restrict__ dzv,
                                                     const float* __restrict__ Qi, const float* __restrict__ Pi,
                                                     float* __restrict__ sc, int o0, int o1) {
    const float* v = blockIdx.x ? dzv : dxv;
    const float* Rm = blockIdx.x ? Pi : Qi;
    int outi = blockIdx.x ? o1 : o0;
    __shared__ float S[70][71], T[70][71], A[70][71];
    __shared__ float cs[35], sn[35];
    int tid = threadIdx.x;
    for (int e = tid; e < 4900; e += 256) {
        int i = e / 70, j = e % 70;
        int hi = i > j ? i : j, lo = i > j ? j : i;
        float val = v[(hi * (hi + 1)) / 2 + lo];
        S[i][j] = (i == j) ? val : val * SQHf;
        A[i][j] = Rm[e];
    }
    __syncthreads();
    for (int e = tid; e < 4900; e += 256) {
        int i = e / 70, j = e % 70;
        float s = 0.0f;
        for (int k = 0; k < 70; ++k) s += A[k][i] * S[k][j];
        T[i][j] = s;
    }
    __syncthreads();
    for (int e = tid; e < 4900; e += 256) {
        int i = e / 70, j = e % 70;
        float s = 0.0f;
        for (int k = 0; k < 70; ++k) s += T[i][k] * A[k][j];
        S[i][j] = s;
    }
    __syncthreads();
    for (int sw = 0; sw < 6; ++sw) {
        for (int rr = 0; rr < 69; ++rr) {
            if (tid < 35) {
                int p = jac_f(tid, rr), q = jac_f(69 - tid, rr);
                float app = S[p][p], aqq = S[q][q], apq = S[p][q];
                float cc = 1.0f, ss = 0.0f;
                float denom = fabsf(app) + fabsf(aqq);
                if (fabsf(apq) > 1e-12f * denom + 1e-30f) {
                    float tau = (aqq - app) / (2.0f * apq);
                    float t = ((tau >= 0.0f) ? 1.0f : -1.0f) / (fabsf(tau) + sqrtf(1.0f + tau * tau));
                    cc = 1.0f / sqrtf(1.0f + t * t);
                    ss = t * cc;
                }
                cs[tid] = cc;
                sn[tid] = ss;
            }
            __syncthreads();
            for (int t = tid; t < 1225; t += 256) {
                int a = t / 35, b = t - a * 35;
                int pa = jac_f(a, rr), qa = jac_f(69 - a, rr);
                int pb = jac_f(b, rr), qb = jac_f(69 - b, rr);
                float ca = cs[a], sa = sn[a], cb = cs[b], sb = sn[b];
                float m00 = S[pa][pb], m01 = S[pa][qb], m10 = S[qa][pb], m11 = S[qa][qb];
                float r00 = ca * m00 - sa * m10, r01 = ca * m01 - sa * m11;
                float r10 = sa * m00 + ca * m10, r11 = sa * m01 + ca * m11;
                S[pa][pb] = cb * r00 - sb * r01;
                S[pa][qb] = sb * r00 + cb * r01;
                S[qa][pb] = cb * r10 - sb * r11;
                S[qa][qb] = sb * r10 + cb * r11;
            }
            __syncthreads();
        }
    }
    __shared__ float red[256];
    float mn = 1e30f;
    for (int i = tid; i < 70; i += 256) mn = fminf(mn, S[i][i]);
    red[tid] = mn;
    __syncthreads();
    for (int o = 128; o; o >>= 1) {
        if (tid < o) red[tid] = fminf(red[tid], red[tid + o]);
        __syncthreads();
    }
    if (tid == 0) sc[outi] = red[0];
}

// ---------- scalar kernels ----------
__global__ void k_pred_scalars(float* sc) {
    float l0a = sc[11], l0b = sc[12];
    float sa = (l0a < 0.0f) ? -1.0f / l0a : 20.0f;
    float sb = (l0b < 0.0f) ? -1.0f / l0b : 20.0f;
    float alpha = fminf(0.5f, 0.9f * sa);
    float beta = fminf(0.5f, 0.9f * sb);
    float minab = fminf(alpha, beta);
    sc[2] = alpha;
    sc[3] = beta;
    sc[4] = minab;
    float mu = sc[0];
    sc[5] = (mu > 1e-6f && minab >= 0.57735026918962576f) ? fmaxf(1.0f, 3.0f * minab * minab) : 1.0f;
}
__global__ void k_sigma(float* sc) {
    float dn = sc[7], xz = sc[1], e = sc[5];
    float frac = dn / xz;
    float fs = (dn < 0.0f) ? 1.0f : frac;
    float sig = (dn < 0.0f) ? 0.8f : fminf(1.0f, powf(fs, e));
    sc[6] = sig;
    sc[13] = sig * sc[0];
    sc[8] = 0.9f + 0.09f * sc[4];
}
__global__ void k_corr_scalars(float* sc) {
    float g2 = sc[8];
    float l0a = sc[14], l0b = sc[15];
    float sa = (l0a < 0.0f) ? -1.0f / l0a : 20.0f;
    float sb = (l0b < 0.0f) ? -1.0f / l0b : 20.0f;
    sc[9] = fminf(0.5f, g2 * sa);
    sc[10] = fminf(0.5f, g2 * sb);
}

// ---------- out = a*u + b*v ----------
__global__ void k_axpby(const float* __restrict__ u, const float* __restrict__ v,
                        float a, float b, float* __restrict__ out, int n) {
    int i = blockIdx.x * 256 + threadIdx.x;
    if (i < n) out[i] = a * u[i] + b * v[i];
}

// ---------- final outputs ----------
__global__ void k_final(const float* __restrict__ x, const float* __restrict__ y, const float* __restrict__ z,
                        const float* __restrict__ dx2, const float* __restrict__ dy2, const float* __restrict__ dz2,
                        const float* __restrict__ normc, const float* __restrict__ sc, float* __restrict__ out) {
    int i = blockIdx.x * 256 + threadIdx.x;
    float a2 = sc[9], b2 = sc[10];
    if (i < 2485) out[i] = x[i] + a2 * dx2[i];
    else if (i < 4485) { int j = i - 2485; out[i] = y[j] + b2 * dy2[j]; }
    else if (i < 6970) { int j = i - 4485; out[i] = z[j] + b2 * dz2[j]; }
    else if (i < 8970) { int j = i - 6970; out[i] = (y[j] + b2 * dy2[j]) * normc[0]; }
}

extern "C" void kernel_launch(void* const* d_in, const int* in_sizes, int n_in,
                              void* d_out, int out_size, void* d_ws, size_t ws_size,
                              hipStream_t stream) {
    const float* x = (const float*)d_in[0];
    const float* y = (const float*)d_in[1];
    const float* z = (const float*)d_in[2];
    const float* A = (const float*)d_in[3];
    const float* b = (const float*)d_in[4];
    const float* c = (const float*)d_in[5];
    const float* normc = (const float*)d_in[6];
    float* out = (float*)d_out;
    float* ws = (float*)d_ws;

    float* SKT = ws;                       // 2000 x 2485 (reused as tri-inverse tmp)
    float* Mm = ws + 4970000;              // 2000 x 2000 -> becomes W = L^-1
    float* S0 = ws + 8970000;
    float* X = S0;
    float* Z = S0 + 4900;
    float* Qu = S0 + 9800;
    float* Pu = S0 + 14700;
    float* Qi = S0 + 19600;
    float* Pi = S0 + 24500;
    float* Zi = S0 + 29400;
    float* W1 = S0 + 44100;
    float* rp = S0 + 83300;
    float* h = S0 + 85300;
    float* dy = S0 + 87300;
    float* dy2 = S0 + 89300;
    float* h2 = S0 + 91300;
    float* Rd = S0 + 93300;
    float* Rc = S0 + 95785;
    float* k1 = S0 + 98270;
    float* k2 = S0 + 100755;
    float* dz = S0 + 103240;
    float* dx = S0 + 105725;
    float* Rc2 = S0 + 108210;
    float* k2b = S0 + 110695;
    float* dz2 = S0 + 113180;
    float* dx2 = S0 + 115665;
    float* tmpv = S0 + 118150;
    float* sc = S0 + 120635;
    float* Linv = S0 + 121000;             // 32 x 4096
    float* v1 = S0 + 253000;               // 2000
    float* pbuf = S0 + 256000;             // 16 x 2485 partials

    // ---- setup ----
    k_smat2<<<39, 256, 0, stream>>>(x, X, z, Z);
    k_chol2<<<2, 256, 0, stream>>>(X, Qu, Z, Pu);
    k_trinv2<<<2, 256, 0, stream>>>(Qu, Qi, Pu, Pi);
    k_mm70<<<1, 256, 0, stream>>>(Pi, 0, Pi, 1, Zi);

    // ---- residuals & mu ----
    k_gemv_rowA<<<2000, 256, 0, stream>>>(A, 2485L, 2485, x, b, -1.0f, rp);
    k_colAT_part<<<dim3(10, 16), 256, 0, stream>>>(A, 2485L, 2000, 2485, y, pbuf);
    k_colAT_fin<<<10, 256, 0, stream>>>(pbuf, 16, 2485, c, z, -1.0f, Rd);
    k_dots_init<<<1, 256, 0, stream>>>(x, z, sc);

    // ---- Rc ----
    k_rc_chain<<<1, 256, 0, stream>>>(X, Z, Pu, Pi, W1, Rc);

    // ---- SKT ; Mmat = A * SKT^T (lower) ----
    k_skmult<<<2000, 256, 0, stream>>>(X, Zi, A, 2485L, SKT, 2485L);
    k_gemm_nt<<<dim3(32, 32), 256, 0, stream>>>(A, 2485L, SKT, 2485L, Mm, 2000L,
                                                2000, 2000, 2485, 1.0f, 0.0f, 1);

    // ---- Cholesky of Mmat (blocked) ----
    for (int jb = 0; jb < 2000; jb += 64) {
        int nb = (2000 - jb) < 64 ? (2000 - jb) : 64;
        float* Lslot = Linv + (long)(jb / 64) * 4096;
        k_chol_diag_inv<<<1, 256, 0, stream>>>(Mm, 2000L, jb, nb, Lslot);
        int rows = 2000 - jb - nb;
        if (rows > 0) {
            int gb = (rows + 63) / 64;
            k_panel_trsm<<<gb, 256, 0, stream>>>(Mm, 2000L, jb, nb, 2000, Lslot);
            const float* pan = Mm + (size_t)(jb + nb) * 2000 + jb;
            float* csub = Mm + (size_t)(jb + nb) * 2000 + (jb + nb);
            k_gemm_nt<<<dim3(gb, gb), 256, 0, stream>>>(pan, 2000L, pan, 2000L, csub, 2000L,
                                                        rows, rows, nb, -1.0f, 1.0f, 1);
        }
    }

    // ---- W = L^-1 in place over Mm (level-batched doubling) ----
    k_zero_upper<<<dim3(32, 32), 256, 0, stream>>>(Mm, 2000);
    k_copy_diaginv<<<32, 256, 0, stream>>>(Mm, 2000L, 2000, Linv);
    for (int bs = 64; bs < 2000; bs *= 2) {
        Pairs16 pl;
        int np = 0, maxM = 0, toff = 0;
        for (int p0 = 0; p0 + bs < 2000; p0 += 2 * bs) {
            int hh = bs;
            int nn = (2 * bs < 2000 - p0) ? 2 * bs : (2000 - p0);
            pl.q[np].x = p0; pl.q[np].y = hh; pl.q[np].z = nn; pl.q[np].w = toff;
            toff += (nn - hh) * hh;
            if (nn - hh > maxM) maxM = nn - hh;
            ++np;
        }
        if (np == 0) continue;
        dim3 g((bs + 63) / 64, (maxM + 63) / 64, np);
        k_tri_phaseA<<<g, 256, 0, stream>>>(Mm, 2000L, SKT, pl, np);
        k_tri_phaseB<<<g, 256, 0, stream>>>(Mm, 2000L, SKT, pl, np);
    }

    // ---- predictor ----
    k_skmult<<<1, 256, 0, stream>>>(X, Zi, Rd, 0L, k1, 0L);
    k_skmult<<<1, 256, 0, stream>>>(Pi, Pi, Rc, 0L, k2, 0L);
    k_axpby<<<10, 256, 0, stream>>>(k1, k2, 1.0f, -1.0f, tmpv, 2485);
    k_gemv_rowA<<<2000, 256, 0, stream>>>(A, 2485L, 2485, tmpv, rp, 1.0f, h);
    k_trimv_low<<<2000, 256, 0, stream>>>(Mm, 2000L, 2000, h, v1);
    k_trimvT_part<<<dim3(8, 16), 256, 0, stream>>>(Mm, 2000L, 2000, v1, pbuf);
    k_part_reduce<<<8, 256, 0, stream>>>(pbuf, 16, 2000, dy);
    k_colAT_part<<<dim3(10, 16), 256, 0, stream>>>(A, 2485L, 2000, 2485, dy, pbuf);
    k_colAT_fin<<<10, 256, 0, stream>>>(pbuf, 16, 2485, Rd, (const float*)0, -1.0f, dz);
    k_skmult<<<1, 256, 0, stream>>>(X, Zi, dz, 0L, tmpv, 0L);
    k_axpby<<<10, 256, 0, stream>>>(x, tmpv, -1.0f, -1.0f, dx, 2485);

    // ---- predictor step lengths ----
    k_steplen_eig<<<2, 256, 0, stream>>>(dx, dz, Qi, Pi, sc, 11, 12);
    k_pred_scalars<<<1, 1, 0, stream>>>(sc);
    k_dot_new<<<1, 256, 0, stream>>>(x, dx, z, dz, sc);
    k_sigma<<<1, 1, 0, stream>>>(sc);

    // ---- corrector ----
    k_rc2_chain<<<1, 256, 0, stream>>>(dx, dz, Pu, Pi, W1, sc, Rc2);
    k_skmult<<<1, 256, 0, stream>>>(Pi, Pi, Rc2, 0L, k2b, 0L);
    k_axpby<<<10, 256, 0, stream>>>(k1, k2b, 1.0f, -1.0f, tmpv, 2485);
    k_gemv_rowA<<<2000, 256, 0, stream>>>(A, 2485L, 2485, tmpv, rp, 1.0f, h2);
    k_trimv_low<<<2000, 256, 0, stream>>>(Mm, 2000L, 2000, h2, v1);
    k_trimvT_part<<<dim3(8, 16), 256, 0, stream>>>(Mm, 2000L, 2000, v1, pbuf);
    k_part_reduce<<<8, 256, 0, stream>>>(pbuf, 16, 2000, dy2);
    k_colAT_part<<<dim3(10, 16), 256, 0, stream>>>(A, 2485L, 2000, 2485, dy2, pbuf);
    k_colAT_fin<<<10, 256, 0, stream>>>(pbuf, 16, 2485, Rd, (const float*)0, -1.0f, dz2);
    k_skmult<<<1, 256, 0, stream>>>(X, Zi, dz2, 0L, tmpv, 0L);
    k_axpby<<<10, 256, 0, stream>>>(k2b, tmpv, 1.0f, -1.0f, dx2, 2485);

    // ---- corrector step lengths ----
    k_steplen_eig<<<2, 256, 0, stream>>>(dx2, dz2, Qi, Pi, sc, 14, 15);
    k_corr_scalars<<<1, 1, 0, stream>>>(sc);

    // ---- outputs ----
    k_final<<<36, 256, 0, stream>>>(x, y, z, dx2, dy2, dz2, normc, sc, out);
}